// Round 4
// baseline (5214.622 us; speedup 1.0000x reference)
//
#include <hip/hip_runtime.h>
#include <hip/hip_bf16.h>

// HyperPatchInvertedResidual: per-patch hyper-conv pipeline with global BNs.
// b=16, c=32, H=W=128, 8x8 patches of 16x16 (+1 halo -> 18x18), HID=192.
// G = 16*64 = 1024 groups.

#define HID 192
#define SP1 324   // 18*18
#define SP2 256   // 16*16
#define HPAR 14016
#define R1 6144   // 32*192
#define R2 7872   // R1 + 192*9
#define NGRP 1024
#define PSTR 36   // patch LDS row stride (halves): conflict-free frag reads

typedef __hip_bfloat16 bf16;
typedef __attribute__((ext_vector_type(4))) unsigned short ushort4v;
typedef __attribute__((ext_vector_type(4))) short short4v;
typedef __attribute__((ext_vector_type(8))) short short8v;
typedef __attribute__((ext_vector_type(4))) float f32x4;
union Frag { short4v h[2]; short8v v; };

__device__ __forceinline__ float b2f(unsigned short u) {
  __hip_bfloat16_raw r; r.x = u;
  return __bfloat162float((bf16)r);
}
__device__ __forceinline__ unsigned short f2b(float f) {
  union { bf16 b; unsigned short u; } c;
  c.b = __float2bfloat16(f);
  return c.u;
}
// XCD-affinity remap: all 64 groups of one batch bi land on XCD bi%8.
__device__ __forceinline__ int remap_g(int blk) {
  int x = blk & 7, q = blk >> 3;
  return (((q >> 6) << 3) + x) * 64 + (q & 63);
}

// ---------------- K1: stage1 1x1 conv 32->192 via MFMA ----------------------
// y1[192,324] = w1[192,32] @ patch[32,324] per group; one 16x16x32 MFMA per tile.
__global__ __launch_bounds__(256) void k1_stage1(
    const float* __restrict__ x, const float* __restrict__ s,
    bf16* __restrict__ y1) {
  int g = remap_g(blockIdx.x);
  int bi = g >> 6, fi = (g >> 3) & 7, fj = g & 7;
  __shared__ unsigned short wlds[6144];          // [o=192][ci=32]
  __shared__ unsigned short plds[336 * PSTR];    // [sp=336][ci], stride 36
  __shared__ unsigned short ytile[4][768];       // per-wave [48 o][16 sp] repack
  int tid = threadIdx.x;
  const float* sg = s + (size_t)bi * HPAR * 64 + fi * 8 + fj;
  for (int k = tid; k < 6144; k += 256) {
    int o = k >> 5, ci = k & 31;
    wlds[k] = f2b(sg[(size_t)(o * 32 + ci) * 64]);
  }
  const float* xb = x + (size_t)bi * 32 * 128 * 128;
  for (int idx = tid; idx < 32 * SP1; idx += 256) {
    int ci = idx / SP1, sp = idx - ci * SP1;
    int a = sp / 18, b = sp - a * 18;
    int r = fi * 16 + a - 1; r = r < 0 ? -r : (r > 127 ? 254 - r : r);
    int c = fj * 16 + b - 1; c = c < 0 ? -c : (c > 127 ? 254 - c : c);
    plds[sp * PSTR + ci] = f2b(xb[((size_t)ci * 128 + r) * 128 + c]);
  }
  for (int i = tid; i < 12 * PSTR; i += 256) plds[SP1 * PSTR + i] = 0;  // pad rows
  __syncthreads();

  int w = tid >> 6, l = tid & 63;
  int lj = l & 15, kg = l >> 4;
  Frag af[3];
#pragma unroll
  for (int i = 0; i < 3; ++i) {   // wave w owns o-tiles {w, w+4, w+8}
    int o = (w + 4 * i) * 16 + lj;
    af[i].h[0] = *(const short4v*)(wlds + o * 32 + 4 * kg);
    af[i].h[1] = *(const short4v*)(wlds + o * 32 + 16 + 4 * kg);
  }
  unsigned short* yt = ytile[w];
  unsigned short* yg = (unsigned short*)y1 + (size_t)g * HID * SP1;
  for (int st = 0; st < 21; ++st) {
    int sp0 = st * 16;
    const unsigned short* pb = plds + (sp0 + lj) * PSTR + 4 * kg;
    Frag bfr;
    bfr.h[0] = *(const short4v*)(pb);
    bfr.h[1] = *(const short4v*)(pb + 16);
    f32x4 acc[3];
#pragma unroll
    for (int i = 0; i < 3; ++i) {
      f32x4 z = {0.f, 0.f, 0.f, 0.f};
      acc[i] = __builtin_amdgcn_mfma_f32_16x16x32_bf16(af[i].v, bfr.v, z, 0, 0, 0);
    }
    // C/D layout: lane holds D[row=kg*4+r][col=lj]  (row->o, col->sp)
#pragma unroll
    for (int i = 0; i < 3; ++i)
#pragma unroll
      for (int r = 0; r < 4; ++r)
        yt[(i * 16 + kg * 4 + r) * 16 + lj] = f2b(acc[i][r]);
    __builtin_amdgcn_wave_barrier();
    // wave-local repack: 3 x short4 (8B) stores per lane
#pragma unroll
    for (int c = 0; c < 3; ++c) {
      int u = l + 64 * c;
      int ol = u >> 2, seg = u & 3;
      int o = (w + 4 * (ol >> 4)) * 16 + (ol & 15);
      if (sp0 + seg * 4 < SP1) {
        short4v v = *(const short4v*)(yt + u * 4);
        *(short4v*)(yg + (size_t)o * SP1 + sp0 + seg * 4) = v;
      }
    }
    __builtin_amdgcn_wave_barrier();
  }
}

// ---------------- stats: per-channel sum & sumsq over [G][CH][SPL] ----------
__global__ __launch_bounds__(256) void k_stats(
    const bf16* __restrict__ src, int CH, int SPL, int gPerBlk,
    float* __restrict__ sums, float* __restrict__ sqs) {
  int ch = blockIdx.x % CH;
  int g0 = (blockIdx.x / CH) * gPerBlk;
  int n4 = SPL >> 2;
  int wv = threadIdx.x >> 6, lane = threadIdx.x & 63;
  float s0 = 0.f, s1 = 0.f;
  for (int gg = wv; gg < gPerBlk; gg += 4) {
    const unsigned short* p =
        (const unsigned short*)(src + ((size_t)(g0 + gg) * CH + ch) * SPL);
    for (int j = lane; j < n4; j += 64) {
      ushort4v u = *(const ushort4v*)(p + 4 * j);
      float v0 = b2f(u.x), v1 = b2f(u.y), v2 = b2f(u.z), v3 = b2f(u.w);
      s0 += v0 + v1 + v2 + v3;
      s1 += v0 * v0 + v1 * v1 + v2 * v2 + v3 * v3;
    }
  }
#pragma unroll
  for (int off = 32; off; off >>= 1) {
    s0 += __shfl_down(s0, off);
    s1 += __shfl_down(s1, off);
  }
  __shared__ float red[8];
  if (lane == 0) { red[wv] = s0; red[4 + wv] = s1; }
  __syncthreads();
  if (threadIdx.x == 0) {
    float a = red[0] + red[1] + red[2] + red[3];
    float b = red[4] + red[5] + red[6] + red[7];
    atomicAdd(&sums[ch], a);
    atomicAdd(&sqs[ch], b);
  }
}

// ---------------- bn params: scale/shift from sums --------------------------
__global__ void k_bnp(const float* __restrict__ sums, const float* __restrict__ sqs,
                      const float* __restrict__ gamma, const float* __restrict__ beta,
                      float* __restrict__ sc, float* __restrict__ sh,
                      int CH, float invN) {
  int ch = threadIdx.x;
  if (ch >= CH) return;
  float m = sums[ch] * invN;
  float v = sqs[ch] * invN - m * m;
  float scale = gamma[ch] * rsqrtf(v + 1e-5f);
  sc[ch] = scale;
  sh[ch] = beta[ch] - m * scale;
}

// ---------------- K3: bn1+relu6 then 3x3 depthwise (valid) ------------------
// 8 channels/chunk, 24 chunks. Thread computes 2 units of (row, 4-col chunk):
// float4 LDS window reads (row stride 20), ushort4 vector stores.
__global__ __launch_bounds__(256) void k3_dw(
    const bf16* __restrict__ y1, const float* __restrict__ s,
    const float* __restrict__ sc1, const float* __restrict__ sh1,
    bf16* __restrict__ y2) {
  int g = remap_g(blockIdx.x);
  int bi = g >> 6, fi = (g >> 3) & 7, fj = g & 7;
  const float* sg2 = s + (size_t)bi * HPAR * 64 + fi * 8 + fj + (size_t)R1 * 64;
  __shared__ float tile[8 * 360];   // [c8][r*20 + c], 18 rows x 18 cols used
  __shared__ float w9s[72];
  int tid = threadIdx.x;
  int ch = tid >> 5, l = tid & 31;
  for (int cc = 0; cc < 24; ++cc) {
    if (cc) __syncthreads();
    for (int u = tid; u < 648; u += 256) {       // 8 ch x 81 ushort4
      int c8 = u / 81, j = u - c8 * 81;
      int o = cc * 8 + c8;
      ushort4v v = *(const ushort4v*)((const unsigned short*)y1 +
                                      ((size_t)g * HID + o) * SP1 + 4 * j);
      float scv = sc1[o], shv = sh1[o];
#pragma unroll
      for (int e = 0; e < 4; ++e) {
        int sp = 4 * j + e;
        int r = sp / 18, c = sp - r * 18;
        float vv = b2f(((const unsigned short*)&v)[e]) * scv + shv;
        tile[c8 * 360 + r * 20 + c] = fminf(fmaxf(vv, 0.f), 6.f);
      }
    }
    if (tid < 72) {
      int c8 = tid / 9, k = tid - c8 * 9;
      w9s[tid] = sg2[(size_t)((cc * 8 + c8) * 9 + k) * 64];
    }
    __syncthreads();
    int o = cc * 8 + ch;
    const float* tch = &tile[ch * 360];
    float wk[9];
#pragma unroll
    for (int k = 0; k < 9; ++k) wk[k] = w9s[ch * 9 + k];
    unsigned short* yrow = (unsigned short*)y2 + ((size_t)g * HID + o) * SP2;
#pragma unroll
    for (int k = 0; k < 2; ++k) {
      int u2 = l + 32 * k;
      int row = u2 >> 2, c4 = (u2 & 3) * 4;
      float a0 = 0.f, a1 = 0.f, a2 = 0.f, a3 = 0.f;
#pragma unroll
      for (int di = 0; di < 3; ++di) {
        const float* rp = tch + (row + di) * 20 + c4;
        float4 f = *(const float4*)rp;
        float f4 = rp[4], f5 = rp[5];
        float w0 = wk[di * 3], w1 = wk[di * 3 + 1], w2 = wk[di * 3 + 2];
        a0 += f.x * w0 + f.y * w1 + f.z * w2;
        a1 += f.y * w0 + f.z * w1 + f.w * w2;
        a2 += f.z * w0 + f.w * w1 + f4 * w2;
        a3 += f.w * w0 + f4 * w1 + f5 * w2;
      }
      ushort4v ov;
      ov.x = f2b(a0); ov.y = f2b(a1); ov.z = f2b(a2); ov.w = f2b(a3);
      *(ushort4v*)(yrow + row * 16 + c4) = ov;
    }
  }
}

// ---------------- K5: bn2+relu6 then 1x1 conv 192->32 -----------------------
__global__ __launch_bounds__(256) void k5_stage3(
    const bf16* __restrict__ y2, const float* __restrict__ s,
    const float* __restrict__ sc2, const float* __restrict__ sh2,
    bf16* __restrict__ y3) {
  int g = remap_g(blockIdx.x);
  int bi = g >> 6, fi = (g >> 3) & 7, fj = g & 7;
  const float* sg = s + (size_t)bi * HPAR * 64 + fi * 8 + fj;
  __shared__ __align__(16) float w3s[6144];      // [o*32 + o2]
  __shared__ __align__(16) float tile[32 * SP2]; // [oo*256 + sp]
  int tid = threadIdx.x;
  for (int k = tid; k < 6144; k += 256) {
    int o = k >> 5, o2 = k & 31;
    w3s[k] = sg[(size_t)(R2 + o2 * HID + o) * 64];
  }
  float acc[8][4];
#pragma unroll
  for (int a = 0; a < 8; ++a)
#pragma unroll
    for (int b = 0; b < 4; ++b) acc[a][b] = 0.f;
  int wv = tid >> 6;    // 4 waves -> o2 block of 8
  int spg = tid & 63;   // sp group of 4
  const float4* w4 = (const float4*)w3s;
  const float4* t4 = (const float4*)tile;
  for (int oc = 0; oc < 6; ++oc) {
    __syncthreads();
    for (int u = tid; u < 2048; u += 256) {      // 32 rows x 64 ushort4
      int t = u >> 6, j = u & 63;
      int o = oc * 32 + t;
      ushort4v v = *(const ushort4v*)((const unsigned short*)y2 +
                                      ((size_t)g * HID + o) * SP2 + 4 * j);
      float scv = sc2[o], shv = sh2[o];
      float4 f;
      f.x = fminf(fmaxf(b2f(v.x) * scv + shv, 0.f), 6.f);
      f.y = fminf(fmaxf(b2f(v.y) * scv + shv, 0.f), 6.f);
      f.z = fminf(fmaxf(b2f(v.z) * scv + shv, 0.f), 6.f);
      f.w = fminf(fmaxf(b2f(v.w) * scv + shv, 0.f), 6.f);
      *(float4*)&tile[t * SP2 + 4 * j] = f;
    }
    __syncthreads();
    for (int t = 0; t < 32; ++t) {
      int o = oc * 32 + t;
      float4 tv = t4[t * 64 + spg];
      float4 wa = w4[o * 8 + wv * 2];
      float4 wb = w4[o * 8 + wv * 2 + 1];
      float wk[8] = {wa.x, wa.y, wa.z, wa.w, wb.x, wb.y, wb.z, wb.w};
#pragma unroll
      for (int a = 0; a < 8; ++a) {
        acc[a][0] += wk[a] * tv.x;
        acc[a][1] += wk[a] * tv.y;
        acc[a][2] += wk[a] * tv.z;
        acc[a][3] += wk[a] * tv.w;
      }
    }
  }
#pragma unroll
  for (int a = 0; a < 8; ++a) {
    int o2 = wv * 8 + a;
    ushort4v ov;
    ov.x = f2b(acc[a][0]); ov.y = f2b(acc[a][1]);
    ov.z = f2b(acc[a][2]); ov.w = f2b(acc[a][3]);
    *(ushort4v*)((unsigned short*)y3 + ((size_t)g * 32 + o2) * SP2 + spg * 4) = ov;
  }
}

// ---------------- K7: bn3 + residual + scatter back (4 elems/thread) --------
__global__ __launch_bounds__(256) void k7_out(
    const float* __restrict__ x, const bf16* __restrict__ y3,
    const float* __restrict__ sc3, const float* __restrict__ sh3,
    float* __restrict__ out) {
  int idx = (blockIdx.x * 256 + threadIdx.x) * 4;  // 16*32*128*128 total
  int wcol = idx & 127;
  int hrow = (idx >> 7) & 127;
  int o2 = (idx >> 14) & 31;
  int bi = idx >> 19;
  int g = bi * 64 + (hrow >> 4) * 8 + (wcol >> 4);
  ushort4v u = *(const ushort4v*)((const unsigned short*)y3 +
                                  ((size_t)g * 32 + o2) * SP2 +
                                  ((hrow & 15) << 4) + (wcol & 15));
  float4 xv = *(const float4*)(x + idx);
  float sc = sc3[o2], sh = sh3[o2];
  float4 ov;
  ov.x = xv.x + b2f(u.x) * sc + sh;
  ov.y = xv.y + b2f(u.y) * sc + sh;
  ov.z = xv.z + b2f(u.z) * sc + sh;
  ov.w = xv.w + b2f(u.w) * sc + sh;
  *(float4*)(out + idx) = ov;
}

extern "C" void kernel_launch(void* const* d_in, const int* in_sizes, int n_in,
                              void* d_out, int out_size, void* d_ws, size_t ws_size,
                              hipStream_t stream) {
  const float* x  = (const float*)d_in[0];
  const float* s  = (const float*)d_in[1];
  const float* g1 = (const float*)d_in[2];
  const float* b1 = (const float*)d_in[3];
  const float* g2 = (const float*)d_in[4];
  const float* b2 = (const float*)d_in[5];
  const float* g3 = (const float*)d_in[6];
  const float* b3 = (const float*)d_in[7];
  float* out = (float*)d_out;

  char* ws = (char*)d_ws;
  float* stats = (float*)ws;
  float* sum1 = stats;        float* sq1 = stats + 192;
  float* sum2 = stats + 384;  float* sq2 = stats + 576;
  float* sum3 = stats + 768;  float* sq3 = stats + 800;
  float* sc1 = stats + 1024;  float* sh1 = stats + 1216;
  float* sc2 = stats + 1408;  float* sh2 = stats + 1600;
  float* sc3 = stats + 1792;  float* sh3 = stats + 1824;
  bf16* y1 = (bf16*)(ws + 8192);                       // 1024*192*324 bf16
  bf16* y2 = y1 + (size_t)NGRP * HID * SP1;            // 1024*192*256 bf16
  bf16* y3 = y1;                                       // alias: y1 dead by K5

  hipMemsetAsync(stats, 0, 832 * sizeof(float), stream);

  k1_stage1<<<NGRP, 256, 0, stream>>>(x, s, y1);
  k_stats<<<192 * 64, 256, 0, stream>>>(y1, HID, SP1, 16, sum1, sq1);
  k_bnp<<<1, 192, 0, stream>>>(sum1, sq1, g1, b1, sc1, sh1, HID, 1.f / (NGRP * (float)SP1));
  k3_dw<<<NGRP, 256, 0, stream>>>(y1, s, sc1, sh1, y2);
  k_stats<<<192 * 64, 256, 0, stream>>>(y2, HID, SP2, 16, sum2, sq2);
  k_bnp<<<1, 192, 0, stream>>>(sum2, sq2, g2, b2, sc2, sh2, HID, 1.f / (NGRP * (float)SP2));
  k5_stage3<<<NGRP, 256, 0, stream>>>(y2, s, sc2, sh2, y3);
  k_stats<<<32 * 64, 256, 0, stream>>>(y3, 32, SP2, 16, sum3, sq3);
  k_bnp<<<1, 32, 0, stream>>>(sum3, sq3, g3, b3, sc3, sh3, 32, 1.f / (NGRP * (float)SP2));
  k7_out<<<8192, 256, 0, stream>>>(x, y3, sc3, sh3, out);
}

// Round 5
// 403.283 us; speedup vs baseline: 12.9304x; 12.9304x over previous
//
#include <hip/hip_runtime.h>
#include <hip/hip_bf16.h>

// HyperPatchInvertedResidual: per-patch hyper-conv pipeline with global BNs.
// b=16, c=32, H=W=128, 8x8 patches of 16x16 (+1 halo -> 18x18), HID=192.
// G = 16*64 = 1024 groups.

#define HID 192
#define SP1 324   // 18*18
#define SP2 256   // 16*16
#define HPAR 14016
#define R1 6144   // 32*192
#define R2 7872   // R1 + 192*9
#define NGRP 1024
#define PSTR 36   // patch LDS row stride (halves): conflict-free frag reads

typedef __hip_bfloat16 bf16;
typedef __attribute__((ext_vector_type(4))) unsigned short ushort4v;
typedef __attribute__((ext_vector_type(4))) short short4v;
typedef __attribute__((ext_vector_type(8))) short short8v;
typedef __attribute__((ext_vector_type(4))) float f32x4;
union Frag { short4v h[2]; short8v v; };

__device__ __forceinline__ float b2f(unsigned short u) {
  __hip_bfloat16_raw r; r.x = u;
  return __bfloat162float((bf16)r);
}
__device__ __forceinline__ unsigned short f2b(float f) {
  union { bf16 b; unsigned short u; } c;
  c.b = __float2bfloat16(f);
  return c.u;
}
// XCD-affinity remap: all 64 groups of one batch bi land on XCD bi%8.
__device__ __forceinline__ int remap_g(int blk) {
  int x = blk & 7, q = blk >> 3;
  return (((q >> 6) << 3) + x) * 64 + (q & 63);
}

// ---------------- K1: stage1 1x1 conv 32->192 via MFMA ----------------------
// y1[192,324] = w1[192,32] @ patch[32,324] per group; one 16x16x32 MFMA per tile.
__global__ __launch_bounds__(256) void k1_stage1(
    const float* __restrict__ x, const float* __restrict__ s,
    bf16* __restrict__ y1) {
  int g = remap_g(blockIdx.x);
  int bi = g >> 6, fi = (g >> 3) & 7, fj = g & 7;
  __shared__ unsigned short wlds[6144];          // [o=192][ci=32]
  __shared__ unsigned short plds[336 * PSTR];    // [sp=336][ci], stride 36
  __shared__ unsigned short ytile[4][768];       // per-wave [48 o][16 sp] repack
  int tid = threadIdx.x;
  const float* sg = s + (size_t)bi * HPAR * 64 + fi * 8 + fj;
  for (int k = tid; k < 6144; k += 256) {
    int o = k >> 5, ci = k & 31;
    wlds[k] = f2b(sg[(size_t)(o * 32 + ci) * 64]);
  }
  const float* xb = x + (size_t)bi * 32 * 128 * 128;
  for (int idx = tid; idx < 32 * SP1; idx += 256) {
    int ci = idx / SP1, sp = idx - ci * SP1;
    int a = sp / 18, b = sp - a * 18;
    int r = fi * 16 + a - 1; r = r < 0 ? -r : (r > 127 ? 254 - r : r);
    int c = fj * 16 + b - 1; c = c < 0 ? -c : (c > 127 ? 254 - c : c);
    plds[sp * PSTR + ci] = f2b(xb[((size_t)ci * 128 + r) * 128 + c]);
  }
  for (int i = tid; i < 12 * PSTR; i += 256) plds[SP1 * PSTR + i] = 0;  // pad rows
  __syncthreads();

  int w = tid >> 6, l = tid & 63;
  int lj = l & 15, kg = l >> 4;
  Frag af[3];
#pragma unroll
  for (int i = 0; i < 3; ++i) {   // wave w owns o-tiles {w, w+4, w+8}
    int o = (w + 4 * i) * 16 + lj;
    af[i].h[0] = *(const short4v*)(wlds + o * 32 + 4 * kg);
    af[i].h[1] = *(const short4v*)(wlds + o * 32 + 16 + 4 * kg);
  }
  unsigned short* yt = ytile[w];
  unsigned short* yg = (unsigned short*)y1 + (size_t)g * HID * SP1;
  for (int st = 0; st < 21; ++st) {
    int sp0 = st * 16;
    const unsigned short* pb = plds + (sp0 + lj) * PSTR + 4 * kg;
    Frag bfr;
    bfr.h[0] = *(const short4v*)(pb);
    bfr.h[1] = *(const short4v*)(pb + 16);
    f32x4 acc[3];
#pragma unroll
    for (int i = 0; i < 3; ++i) {
      f32x4 z = {0.f, 0.f, 0.f, 0.f};
      acc[i] = __builtin_amdgcn_mfma_f32_16x16x32_bf16(af[i].v, bfr.v, z, 0, 0, 0);
    }
    // C/D layout: lane holds D[row=kg*4+r][col=lj]  (row->o, col->sp)
#pragma unroll
    for (int i = 0; i < 3; ++i)
#pragma unroll
      for (int r = 0; r < 4; ++r)
        yt[(i * 16 + kg * 4 + r) * 16 + lj] = f2b(acc[i][r]);
    __builtin_amdgcn_wave_barrier();
    // wave-local repack: 3 x short4 (8B) stores per lane
#pragma unroll
    for (int c = 0; c < 3; ++c) {
      int u = l + 64 * c;
      int ol = u >> 2, seg = u & 3;
      int o = (w + 4 * (ol >> 4)) * 16 + (ol & 15);
      if (sp0 + seg * 4 < SP1) {
        short4v v = *(const short4v*)(yt + u * 4);
        *(short4v*)(yg + (size_t)o * SP1 + sp0 + seg * 4) = v;
      }
    }
    __builtin_amdgcn_wave_barrier();
  }
}

// ---------------- stats: per-channel sum & sumsq over [G][CH][SPL] ----------
__global__ __launch_bounds__(256) void k_stats(
    const bf16* __restrict__ src, int CH, int SPL, int gPerBlk,
    float* __restrict__ sums, float* __restrict__ sqs) {
  int ch = blockIdx.x % CH;
  int g0 = (blockIdx.x / CH) * gPerBlk;
  int n4 = SPL >> 2;
  int wv = threadIdx.x >> 6, lane = threadIdx.x & 63;
  float s0 = 0.f, s1 = 0.f;
  for (int gg = wv; gg < gPerBlk; gg += 4) {
    const unsigned short* p =
        (const unsigned short*)(src + ((size_t)(g0 + gg) * CH + ch) * SPL);
    for (int j = lane; j < n4; j += 64) {
      ushort4v u = *(const ushort4v*)(p + 4 * j);
      float v0 = b2f(u.x), v1 = b2f(u.y), v2 = b2f(u.z), v3 = b2f(u.w);
      s0 += v0 + v1 + v2 + v3;
      s1 += v0 * v0 + v1 * v1 + v2 * v2 + v3 * v3;
    }
  }
#pragma unroll
  for (int off = 32; off; off >>= 1) {
    s0 += __shfl_down(s0, off);
    s1 += __shfl_down(s1, off);
  }
  __shared__ float red[8];
  if (lane == 0) { red[wv] = s0; red[4 + wv] = s1; }
  __syncthreads();
  if (threadIdx.x == 0) {
    float a = red[0] + red[1] + red[2] + red[3];
    float b = red[4] + red[5] + red[6] + red[7];
    atomicAdd(&sums[ch], a);
    atomicAdd(&sqs[ch], b);
  }
}

// ---------------- bn params: scale/shift from sums --------------------------
__global__ void k_bnp(const float* __restrict__ sums, const float* __restrict__ sqs,
                      const float* __restrict__ gamma, const float* __restrict__ beta,
                      float* __restrict__ sc, float* __restrict__ sh,
                      int CH, float invN) {
  int ch = threadIdx.x;
  if (ch >= CH) return;
  float m = sums[ch] * invN;
  float v = sqs[ch] * invN - m * m;
  float scale = gamma[ch] * rsqrtf(v + 1e-5f);
  sc[ch] = scale;
  sh[ch] = beta[ch] - m * scale;
}

// ---------------- K3: bn1+relu6 then 3x3 depthwise (valid) ------------------
// 8 channels/chunk, 24 chunks. Thread computes 2 units of (row, 4-col chunk):
// float4 LDS window reads (row stride 20), ushort4 vector stores.
__global__ __launch_bounds__(256) void k3_dw(
    const bf16* __restrict__ y1, const float* __restrict__ s,
    const float* __restrict__ sc1, const float* __restrict__ sh1,
    bf16* __restrict__ y2) {
  int g = remap_g(blockIdx.x);
  int bi = g >> 6, fi = (g >> 3) & 7, fj = g & 7;
  const float* sg2 = s + (size_t)bi * HPAR * 64 + fi * 8 + fj + (size_t)R1 * 64;
  __shared__ float tile[8 * 360];   // [c8][r*20 + c], 18 rows x 18 cols used
  __shared__ float w9s[72];
  int tid = threadIdx.x;
  int ch = tid >> 5, l = tid & 31;
  for (int cc = 0; cc < 24; ++cc) {
    if (cc) __syncthreads();
    for (int u = tid; u < 648; u += 256) {       // 8 ch x 81 ushort4
      int c8 = u / 81, j = u - c8 * 81;
      int o = cc * 8 + c8;
      ushort4v v = *(const ushort4v*)((const unsigned short*)y1 +
                                      ((size_t)g * HID + o) * SP1 + 4 * j);
      float scv = sc1[o], shv = sh1[o];
#pragma unroll
      for (int e = 0; e < 4; ++e) {
        int sp = 4 * j + e;
        int r = sp / 18, c = sp - r * 18;
        float vv = b2f(((const unsigned short*)&v)[e]) * scv + shv;
        tile[c8 * 360 + r * 20 + c] = fminf(fmaxf(vv, 0.f), 6.f);
      }
    }
    if (tid < 72) {
      int c8 = tid / 9, k = tid - c8 * 9;
      w9s[tid] = sg2[(size_t)((cc * 8 + c8) * 9 + k) * 64];
    }
    __syncthreads();
    int o = cc * 8 + ch;
    const float* tch = &tile[ch * 360];
    float wk[9];
#pragma unroll
    for (int k = 0; k < 9; ++k) wk[k] = w9s[ch * 9 + k];
    unsigned short* yrow = (unsigned short*)y2 + ((size_t)g * HID + o) * SP2;
#pragma unroll
    for (int k = 0; k < 2; ++k) {
      int u2 = l + 32 * k;
      int row = u2 >> 2, c4 = (u2 & 3) * 4;
      float a0 = 0.f, a1 = 0.f, a2 = 0.f, a3 = 0.f;
#pragma unroll
      for (int di = 0; di < 3; ++di) {
        const float* rp = tch + (row + di) * 20 + c4;
        float4 f = *(const float4*)rp;
        float f4 = rp[4], f5 = rp[5];
        float w0 = wk[di * 3], w1 = wk[di * 3 + 1], w2 = wk[di * 3 + 2];
        a0 += f.x * w0 + f.y * w1 + f.z * w2;
        a1 += f.y * w0 + f.z * w1 + f.w * w2;
        a2 += f.z * w0 + f.w * w1 + f4 * w2;
        a3 += f.w * w0 + f4 * w1 + f5 * w2;
      }
      ushort4v ov;
      ov.x = f2b(a0); ov.y = f2b(a1); ov.z = f2b(a2); ov.w = f2b(a3);
      *(ushort4v*)(yrow + row * 16 + c4) = ov;
    }
  }
}

// ---------------- K5: bn2+relu6 then 1x1 conv 192->32 -----------------------
// (round-3 verbatim: round-4's small-trip staging loop let the compiler fully
//  unroll the oc-loop -> 256 VGPRs + 6.9 GB scratch spill traffic. Reverted.)
__global__ __launch_bounds__(256) void k5_stage3(
    const bf16* __restrict__ y2, const float* __restrict__ s,
    const float* __restrict__ sc2, const float* __restrict__ sh2,
    bf16* __restrict__ y3) {
  int g = blockIdx.x;
  int bi = g >> 6, fi = (g >> 3) & 7, fj = g & 7;
  const float* sg = s + (size_t)bi * HPAR * 64 + fi * 8 + fj;
  __shared__ __align__(16) float w3s[6144];      // [o*32 + o2]
  __shared__ __align__(16) float tile[32 * SP2]; // [oo*256 + sp]
  int tid = threadIdx.x;
  for (int k = tid; k < 6144; k += 256) {
    int o = k >> 5, o2 = k & 31;
    w3s[k] = sg[(size_t)(R2 + o2 * HID + o) * 64];
  }
  float acc[8][4];
#pragma unroll
  for (int a = 0; a < 8; ++a)
#pragma unroll
    for (int b = 0; b < 4; ++b) acc[a][b] = 0.f;
  int wv = tid >> 6;    // 4 waves -> o2 block of 8
  int spg = tid & 63;   // sp group of 4
  const float4* w4 = (const float4*)w3s;
  const float4* t4 = (const float4*)tile;
  for (int oc = 0; oc < 6; ++oc) {
    __syncthreads();
    for (int t = 0; t < 32; ++t) {
      int o = oc * 32 + t;
      float v = __bfloat162float(y2[((size_t)g * HID + o) * SP2 + tid]);
      v = v * sc2[o] + sh2[o];
      tile[t * SP2 + tid] = fminf(fmaxf(v, 0.f), 6.f);
    }
    __syncthreads();
    for (int t = 0; t < 32; ++t) {
      int o = oc * 32 + t;
      float4 tv = t4[t * 64 + spg];
      float4 wa = w4[o * 8 + wv * 2];
      float4 wb = w4[o * 8 + wv * 2 + 1];
      float wk[8] = {wa.x, wa.y, wa.z, wa.w, wb.x, wb.y, wb.z, wb.w};
#pragma unroll
      for (int a = 0; a < 8; ++a) {
        acc[a][0] += wk[a] * tv.x;
        acc[a][1] += wk[a] * tv.y;
        acc[a][2] += wk[a] * tv.z;
        acc[a][3] += wk[a] * tv.w;
      }
    }
  }
#pragma unroll
  for (int a = 0; a < 8; ++a) {
    int o2 = wv * 8 + a;
#pragma unroll
    for (int b = 0; b < 4; ++b)
      y3[((size_t)g * 32 + o2) * SP2 + spg * 4 + b] = __float2bfloat16(acc[a][b]);
  }
}

// ---------------- K7: bn3 + residual + scatter back (4 elems/thread) --------
__global__ __launch_bounds__(256) void k7_out(
    const float* __restrict__ x, const bf16* __restrict__ y3,
    const float* __restrict__ sc3, const float* __restrict__ sh3,
    float* __restrict__ out) {
  int idx = (blockIdx.x * 256 + threadIdx.x) * 4;  // 16*32*128*128 total
  int wcol = idx & 127;
  int hrow = (idx >> 7) & 127;
  int o2 = (idx >> 14) & 31;
  int bi = idx >> 19;
  int g = bi * 64 + (hrow >> 4) * 8 + (wcol >> 4);
  ushort4v u = *(const ushort4v*)((const unsigned short*)y3 +
                                  ((size_t)g * 32 + o2) * SP2 +
                                  ((hrow & 15) << 4) + (wcol & 15));
  float4 xv = *(const float4*)(x + idx);
  float sc = sc3[o2], sh = sh3[o2];
  float4 ov;
  ov.x = xv.x + b2f(u.x) * sc + sh;
  ov.y = xv.y + b2f(u.y) * sc + sh;
  ov.z = xv.z + b2f(u.z) * sc + sh;
  ov.w = xv.w + b2f(u.w) * sc + sh;
  *(float4*)(out + idx) = ov;
}

extern "C" void kernel_launch(void* const* d_in, const int* in_sizes, int n_in,
                              void* d_out, int out_size, void* d_ws, size_t ws_size,
                              hipStream_t stream) {
  const float* x  = (const float*)d_in[0];
  const float* s  = (const float*)d_in[1];
  const float* g1 = (const float*)d_in[2];
  const float* b1 = (const float*)d_in[3];
  const float* g2 = (const float*)d_in[4];
  const float* b2 = (const float*)d_in[5];
  const float* g3 = (const float*)d_in[6];
  const float* b3 = (const float*)d_in[7];
  float* out = (float*)d_out;

  char* ws = (char*)d_ws;
  float* stats = (float*)ws;
  float* sum1 = stats;        float* sq1 = stats + 192;
  float* sum2 = stats + 384;  float* sq2 = stats + 576;
  float* sum3 = stats + 768;  float* sq3 = stats + 800;
  float* sc1 = stats + 1024;  float* sh1 = stats + 1216;
  float* sc2 = stats + 1408;  float* sh2 = stats + 1600;
  float* sc3 = stats + 1792;  float* sh3 = stats + 1824;
  bf16* y1 = (bf16*)(ws + 8192);                       // 1024*192*324 bf16
  bf16* y2 = y1 + (size_t)NGRP * HID * SP1;            // 1024*192*256 bf16
  bf16* y3 = y1;                                       // alias: y1 dead by K5

  hipMemsetAsync(stats, 0, 832 * sizeof(float), stream);

  k1_stage1<<<NGRP, 256, 0, stream>>>(x, s, y1);
  k_stats<<<192 * 64, 256, 0, stream>>>(y1, HID, SP1, 16, sum1, sq1);
  k_bnp<<<1, 192, 0, stream>>>(sum1, sq1, g1, b1, sc1, sh1, HID, 1.f / (NGRP * (float)SP1));
  k3_dw<<<NGRP, 256, 0, stream>>>(y1, s, sc1, sh1, y2);
  k_stats<<<192 * 64, 256, 0, stream>>>(y2, HID, SP2, 16, sum2, sq2);
  k_bnp<<<1, 192, 0, stream>>>(sum2, sq2, g2, b2, sc2, sh2, HID, 1.f / (NGRP * (float)SP2));
  k5_stage3<<<NGRP, 256, 0, stream>>>(y2, s, sc2, sh2, y3);
  k_stats<<<32 * 64, 256, 0, stream>>>(y3, 32, SP2, 16, sum3, sq3);
  k_bnp<<<1, 32, 0, stream>>>(sum3, sq3, g3, b3, sc3, sh3, 32, 1.f / (NGRP * (float)SP2));
  k7_out<<<8192, 256, 0, stream>>>(x, y3, sc3, sh3, out);
}

// Round 6
// 357.772 us; speedup vs baseline: 14.5753x; 1.1272x over previous
//
#include <hip/hip_runtime.h>
#include <hip/hip_bf16.h>

// HyperPatchInvertedResidual: per-patch hyper-conv pipeline with global BNs.
// b=16, c=32, H=W=128, 8x8 patches of 16x16 (+1 halo -> 18x18), HID=192.
// G = 16*64 = 1024 groups.

#define HID 192
#define SP1 324   // 18*18
#define SP2 256   // 16*16
#define HPAR 14016
#define R1 6144   // 32*192
#define R2 7872   // R1 + 192*9
#define NGRP 1024
#define PSTR 36   // patch LDS row stride (halves): conflict-free frag reads
#define WSTR 200  // w3 LDS row stride (halves)

typedef __hip_bfloat16 bf16;
typedef __attribute__((ext_vector_type(4))) unsigned short ushort4v;
typedef __attribute__((ext_vector_type(4))) short short4v;
typedef __attribute__((ext_vector_type(8))) short short8v;
typedef __attribute__((ext_vector_type(4))) float f32x4;
union Frag { short4v h[2]; short8v v; };

__device__ __forceinline__ float b2f(unsigned short u) {
  __hip_bfloat16_raw r; r.x = u;
  return __bfloat162float((bf16)r);
}
__device__ __forceinline__ unsigned short f2b(float f) {
  union { bf16 b; unsigned short u; } c;
  c.b = __float2bfloat16(f);
  return c.u;
}
// XCD-affinity remap: all 64 groups of one batch bi land on XCD bi%8.
__device__ __forceinline__ int remap_g(int blk) {
  int x = blk & 7, q = blk >> 3;
  return (((q >> 6) << 3) + x) * 64 + (q & 63);
}

// ---------------- K1: stage1 1x1 conv 32->192 via MFMA ----------------------
// y1[192,324] = w1[192,32] @ patch[32,324] per group; one 16x16x32 MFMA per tile.
__global__ __launch_bounds__(256) void k1_stage1(
    const float* __restrict__ x, const float* __restrict__ s,
    bf16* __restrict__ y1) {
  int g = remap_g(blockIdx.x);
  int bi = g >> 6, fi = (g >> 3) & 7, fj = g & 7;
  __shared__ unsigned short wlds[6144];          // [o=192][ci=32]
  __shared__ unsigned short plds[336 * PSTR];    // [sp=336][ci], stride 36
  __shared__ unsigned short ytile[4][768];       // per-wave [48 o][16 sp] repack
  int tid = threadIdx.x;
  const float* sg = s + (size_t)bi * HPAR * 64 + fi * 8 + fj;
  for (int k = tid; k < 6144; k += 256) {
    int o = k >> 5, ci = k & 31;
    wlds[k] = f2b(sg[(size_t)(o * 32 + ci) * 64]);
  }
  const float* xb = x + (size_t)bi * 32 * 128 * 128;
  for (int idx = tid; idx < 32 * SP1; idx += 256) {
    int ci = idx / SP1, sp = idx - ci * SP1;
    int a = sp / 18, b = sp - a * 18;
    int r = fi * 16 + a - 1; r = r < 0 ? -r : (r > 127 ? 254 - r : r);
    int c = fj * 16 + b - 1; c = c < 0 ? -c : (c > 127 ? 254 - c : c);
    plds[sp * PSTR + ci] = f2b(xb[((size_t)ci * 128 + r) * 128 + c]);
  }
  for (int i = tid; i < 12 * PSTR; i += 256) plds[SP1 * PSTR + i] = 0;  // pad rows
  __syncthreads();

  int w = tid >> 6, l = tid & 63;
  int lj = l & 15, kg = l >> 4;
  Frag af[3];
#pragma unroll
  for (int i = 0; i < 3; ++i) {   // wave w owns o-tiles {w, w+4, w+8}
    int o = (w + 4 * i) * 16 + lj;
    af[i].h[0] = *(const short4v*)(wlds + o * 32 + 4 * kg);
    af[i].h[1] = *(const short4v*)(wlds + o * 32 + 16 + 4 * kg);
  }
  unsigned short* yt = ytile[w];
  unsigned short* yg = (unsigned short*)y1 + (size_t)g * HID * SP1;
  for (int st = 0; st < 21; ++st) {
    int sp0 = st * 16;
    const unsigned short* pb = plds + (sp0 + lj) * PSTR + 4 * kg;
    Frag bfr;
    bfr.h[0] = *(const short4v*)(pb);
    bfr.h[1] = *(const short4v*)(pb + 16);
    f32x4 acc[3];
#pragma unroll
    for (int i = 0; i < 3; ++i) {
      f32x4 z = {0.f, 0.f, 0.f, 0.f};
      acc[i] = __builtin_amdgcn_mfma_f32_16x16x32_bf16(af[i].v, bfr.v, z, 0, 0, 0);
    }
    // C/D layout: lane holds D[row=kg*4+r][col=lj]  (row->o, col->sp)
#pragma unroll
    for (int i = 0; i < 3; ++i)
#pragma unroll
      for (int r = 0; r < 4; ++r)
        yt[(i * 16 + kg * 4 + r) * 16 + lj] = f2b(acc[i][r]);
    __builtin_amdgcn_wave_barrier();
    // wave-local repack: 3 x short4 (8B) stores per lane
#pragma unroll
    for (int c = 0; c < 3; ++c) {
      int u = l + 64 * c;
      int ol = u >> 2, seg = u & 3;
      int o = (w + 4 * (ol >> 4)) * 16 + (ol & 15);
      if (sp0 + seg * 4 < SP1) {
        short4v v = *(const short4v*)(yt + u * 4);
        *(short4v*)(yg + (size_t)o * SP1 + sp0 + seg * 4) = v;
      }
    }
    __builtin_amdgcn_wave_barrier();
  }
}

// ---------------- stats: per-channel sum & sumsq over [G][CH][SPL] ----------
__global__ __launch_bounds__(256) void k_stats(
    const bf16* __restrict__ src, int CH, int SPL, int gPerBlk,
    float* __restrict__ sums, float* __restrict__ sqs) {
  int ch = blockIdx.x % CH;
  int g0 = (blockIdx.x / CH) * gPerBlk;
  int n4 = SPL >> 2;
  int wv = threadIdx.x >> 6, lane = threadIdx.x & 63;
  float s0 = 0.f, s1 = 0.f;
  for (int gg = wv; gg < gPerBlk; gg += 4) {
    const unsigned short* p =
        (const unsigned short*)(src + ((size_t)(g0 + gg) * CH + ch) * SPL);
    for (int j = lane; j < n4; j += 64) {
      ushort4v u = *(const ushort4v*)(p + 4 * j);
      float v0 = b2f(u.x), v1 = b2f(u.y), v2 = b2f(u.z), v3 = b2f(u.w);
      s0 += v0 + v1 + v2 + v3;
      s1 += v0 * v0 + v1 * v1 + v2 * v2 + v3 * v3;
    }
  }
#pragma unroll
  for (int off = 32; off; off >>= 1) {
    s0 += __shfl_down(s0, off);
    s1 += __shfl_down(s1, off);
  }
  __shared__ float red[8];
  if (lane == 0) { red[wv] = s0; red[4 + wv] = s1; }
  __syncthreads();
  if (threadIdx.x == 0) {
    float a = red[0] + red[1] + red[2] + red[3];
    float b = red[4] + red[5] + red[6] + red[7];
    atomicAdd(&sums[ch], a);
    atomicAdd(&sqs[ch], b);
  }
}

// ---------------- bn params: scale/shift from sums --------------------------
__global__ void k_bnp(const float* __restrict__ sums, const float* __restrict__ sqs,
                      const float* __restrict__ gamma, const float* __restrict__ beta,
                      float* __restrict__ sc, float* __restrict__ sh,
                      int CH, float invN) {
  int ch = threadIdx.x;
  if (ch >= CH) return;
  float m = sums[ch] * invN;
  float v = sqs[ch] * invN - m * m;
  float scale = gamma[ch] * rsqrtf(v + 1e-5f);
  sc[ch] = scale;
  sh[ch] = beta[ch] - m * scale;
}

// ---------------- K3: bn1+relu6 then 3x3 depthwise (valid) ------------------
// 8 channels/chunk, 24 chunks. Thread computes 2 units of (row, 4-col chunk):
// float4 LDS window reads (row stride 20), ushort4 vector stores.
__global__ __launch_bounds__(256) void k3_dw(
    const bf16* __restrict__ y1, const float* __restrict__ s,
    const float* __restrict__ sc1, const float* __restrict__ sh1,
    bf16* __restrict__ y2) {
  int g = remap_g(blockIdx.x);
  int bi = g >> 6, fi = (g >> 3) & 7, fj = g & 7;
  const float* sg2 = s + (size_t)bi * HPAR * 64 + fi * 8 + fj + (size_t)R1 * 64;
  __shared__ float tile[8 * 360];   // [c8][r*20 + c], 18 rows x 18 cols used
  __shared__ float w9s[72];
  int tid = threadIdx.x;
  int ch = tid >> 5, l = tid & 31;
  for (int cc = 0; cc < 24; ++cc) {
    if (cc) __syncthreads();
    for (int u = tid; u < 648; u += 256) {       // 8 ch x 81 ushort4
      int c8 = u / 81, j = u - c8 * 81;
      int o = cc * 8 + c8;
      ushort4v v = *(const ushort4v*)((const unsigned short*)y1 +
                                      ((size_t)g * HID + o) * SP1 + 4 * j);
      float scv = sc1[o], shv = sh1[o];
#pragma unroll
      for (int e = 0; e < 4; ++e) {
        int sp = 4 * j + e;
        int r = sp / 18, c = sp - r * 18;
        float vv = b2f(((const unsigned short*)&v)[e]) * scv + shv;
        tile[c8 * 360 + r * 20 + c] = fminf(fmaxf(vv, 0.f), 6.f);
      }
    }
    if (tid < 72) {
      int c8 = tid / 9, k = tid - c8 * 9;
      w9s[tid] = sg2[(size_t)((cc * 8 + c8) * 9 + k) * 64];
    }
    __syncthreads();
    int o = cc * 8 + ch;
    const float* tch = &tile[ch * 360];
    float wk[9];
#pragma unroll
    for (int k = 0; k < 9; ++k) wk[k] = w9s[ch * 9 + k];
    unsigned short* yrow = (unsigned short*)y2 + ((size_t)g * HID + o) * SP2;
#pragma unroll
    for (int k = 0; k < 2; ++k) {
      int u2 = l + 32 * k;
      int row = u2 >> 2, c4 = (u2 & 3) * 4;
      float a0 = 0.f, a1 = 0.f, a2 = 0.f, a3 = 0.f;
#pragma unroll
      for (int di = 0; di < 3; ++di) {
        const float* rp = tch + (row + di) * 20 + c4;
        float4 f = *(const float4*)rp;
        float f4 = rp[4], f5 = rp[5];
        float w0 = wk[di * 3], w1 = wk[di * 3 + 1], w2 = wk[di * 3 + 2];
        a0 += f.x * w0 + f.y * w1 + f.z * w2;
        a1 += f.y * w0 + f.z * w1 + f.w * w2;
        a2 += f.z * w0 + f.w * w1 + f4 * w2;
        a3 += f.w * w0 + f4 * w1 + f5 * w2;
      }
      ushort4v ov;
      ov.x = f2b(a0); ov.y = f2b(a1); ov.z = f2b(a2); ov.w = f2b(a3);
      *(ushort4v*)(yrow + row * 16 + c4) = ov;
    }
  }
}

// ---------------- K5: bn2+relu6 then 1x1 conv 192->32 via MFMA --------------
// y3[32,256] = W3[32,192] @ bn2relu6(y2)[192,256] per group.
// Operand roles swapped (T first) so D rows = sp -> direct short4 stores.
// Staging transpose [o][sp]->[sp][k] via 4x4 register-block transpose.
__global__ __launch_bounds__(256) void k5_stage3(
    const bf16* __restrict__ y2, const float* __restrict__ s,
    const float* __restrict__ sc2, const float* __restrict__ sh2,
    bf16* __restrict__ y3) {
  int g = remap_g(blockIdx.x);
  int bi = g >> 6, fi = (g >> 3) & 7, fj = g & 7;
  const float* sg = s + (size_t)bi * HPAR * 64 + fi * 8 + fj;
  __shared__ unsigned short bt[256 * PSTR];      // [sp=256][k-chunk=32], stride 36
  __shared__ unsigned short w3lds[32 * WSTR];    // [o2=32][k=192], stride 200
  int tid = threadIdx.x;
  // stage W3 (bf16) once: w3lds[o2][k] = s[R2 + o2*HID + k]
  {
    int o2 = tid >> 3, kb = (tid & 7) * 24;
    const float* wp = sg + (size_t)(R2 + o2 * HID + kb) * 64;
    for (int i = 0; i < 24; ++i)
      w3lds[o2 * WSTR + kb + i] = f2b(wp[(size_t)i * 64]);
  }
  int w = tid >> 6, l = tid & 63;
  int lj = l & 15, kg = l >> 4;
  f32x4 acc[4][2] = {};
  const unsigned short* y2g = (const unsigned short*)y2 + (size_t)g * HID * SP2;
#pragma unroll 1
  for (int kc = 0; kc < 6; ++kc) {
    if (kc) __syncthreads();   // protect bt from previous chunk's readers
    // stage bt[sp][kloc] for k in [kc*32, kc*32+32), bn2+relu6 fused,
    // 4x4 register transpose: 4 ushort4 loads along sp -> 4 ushort4 writes along k
#pragma unroll
    for (int uu = 0; uu < 2; ++uu) {
      int u = tid + 256 * uu;
      int tq = u & 7, spq = u >> 3;           // k-quad, sp-quad
      int o0 = kc * 32 + tq * 4;
      float4 scv = *(const float4*)(sc2 + o0);
      float4 shv = *(const float4*)(sh2 + o0);
      unsigned short hbuf[4][4];
#pragma unroll
      for (int e = 0; e < 4; ++e) {
        ushort4v v = *(const ushort4v*)(y2g + (size_t)(o0 + e) * SP2 + spq * 4);
        float sce = ((const float*)&scv)[e], she = ((const float*)&shv)[e];
#pragma unroll
        for (int j = 0; j < 4; ++j) {
          float f = b2f(((const unsigned short*)&v)[j]) * sce + she;
          hbuf[e][j] = f2b(fminf(fmaxf(f, 0.f), 6.f));
        }
      }
#pragma unroll
      for (int j = 0; j < 4; ++j) {
        ushort4v wv;
        wv.x = hbuf[0][j]; wv.y = hbuf[1][j]; wv.z = hbuf[2][j]; wv.w = hbuf[3][j];
        *(ushort4v*)(bt + (spq * 4 + j) * PSTR + tq * 4) = wv;
      }
    }
    __syncthreads();
    // W3 frags for this k-chunk (re-read from LDS each chunk: no runtime-
    // indexed frag arrays -> no scratch; 4 ds_read_b64 vs 8 MFMAs)
    Frag wf[2];
#pragma unroll
    for (int ot = 0; ot < 2; ++ot) {
      const unsigned short* wp = w3lds + (ot * 16 + lj) * WSTR + kc * 32 + 4 * kg;
      wf[ot].h[0] = *(const short4v*)wp;
      wf[ot].h[1] = *(const short4v*)(wp + 16);
    }
#pragma unroll
    for (int sti = 0; sti < 4; ++sti) {
      const unsigned short* pb = bt + ((w + 4 * sti) * 16 + lj) * PSTR + 4 * kg;
      Frag tf;
      tf.h[0] = *(const short4v*)pb;
      tf.h[1] = *(const short4v*)(pb + 16);
#pragma unroll
      for (int ot = 0; ot < 2; ++ot)
        acc[sti][ot] = __builtin_amdgcn_mfma_f32_16x16x32_bf16(
            tf.v, wf[ot].v, acc[sti][ot], 0, 0, 0);
    }
  }
  // D[m=kg*4+r][n=lj]: m indexes operand-1 (sp), n indexes operand-2 (o2)
  // -> lane holds 4 consecutive sp for one o2: direct short4 stores.
  unsigned short* yg3 = (unsigned short*)y3 + (size_t)g * 32 * SP2;
#pragma unroll
  for (int sti = 0; sti < 4; ++sti) {
    int spb = (w + 4 * sti) * 16 + kg * 4;
#pragma unroll
    for (int ot = 0; ot < 2; ++ot) {
      int o2 = ot * 16 + lj;
      short4v ov;
      ov.x = (short)f2b(acc[sti][ot][0]);
      ov.y = (short)f2b(acc[sti][ot][1]);
      ov.z = (short)f2b(acc[sti][ot][2]);
      ov.w = (short)f2b(acc[sti][ot][3]);
      *(short4v*)(yg3 + (size_t)o2 * SP2 + spb) = ov;
    }
  }
}

// ---------------- K7: bn3 + residual + scatter back (4 elems/thread) --------
__global__ __launch_bounds__(256) void k7_out(
    const float* __restrict__ x, const bf16* __restrict__ y3,
    const float* __restrict__ sc3, const float* __restrict__ sh3,
    float* __restrict__ out) {
  int idx = (blockIdx.x * 256 + threadIdx.x) * 4;  // 16*32*128*128 total
  int wcol = idx & 127;
  int hrow = (idx >> 7) & 127;
  int o2 = (idx >> 14) & 31;
  int bi = idx >> 19;
  int g = bi * 64 + (hrow >> 4) * 8 + (wcol >> 4);
  ushort4v u = *(const ushort4v*)((const unsigned short*)y3 +
                                  ((size_t)g * 32 + o2) * SP2 +
                                  ((hrow & 15) << 4) + (wcol & 15));
  float4 xv = *(const float4*)(x + idx);
  float sc = sc3[o2], sh = sh3[o2];
  float4 ov;
  ov.x = xv.x + b2f(u.x) * sc + sh;
  ov.y = xv.y + b2f(u.y) * sc + sh;
  ov.z = xv.z + b2f(u.z) * sc + sh;
  ov.w = xv.w + b2f(u.w) * sc + sh;
  *(float4*)(out + idx) = ov;
}

extern "C" void kernel_launch(void* const* d_in, const int* in_sizes, int n_in,
                              void* d_out, int out_size, void* d_ws, size_t ws_size,
                              hipStream_t stream) {
  const float* x  = (const float*)d_in[0];
  const float* s  = (const float*)d_in[1];
  const float* g1 = (const float*)d_in[2];
  const float* b1 = (const float*)d_in[3];
  const float* g2 = (const float*)d_in[4];
  const float* b2 = (const float*)d_in[5];
  const float* g3 = (const float*)d_in[6];
  const float* b3 = (const float*)d_in[7];
  float* out = (float*)d_out;

  char* ws = (char*)d_ws;
  float* stats = (float*)ws;
  float* sum1 = stats;        float* sq1 = stats + 192;
  float* sum2 = stats + 384;  float* sq2 = stats + 576;
  float* sum3 = stats + 768;  float* sq3 = stats + 800;
  float* sc1 = stats + 1024;  float* sh1 = stats + 1216;
  float* sc2 = stats + 1408;  float* sh2 = stats + 1600;
  float* sc3 = stats + 1792;  float* sh3 = stats + 1824;
  bf16* y1 = (bf16*)(ws + 8192);                       // 1024*192*324 bf16
  bf16* y2 = y1 + (size_t)NGRP * HID * SP1;            // 1024*192*256 bf16
  bf16* y3 = y1;                                       // alias: y1 dead by K5

  hipMemsetAsync(stats, 0, 832 * sizeof(float), stream);

  k1_stage1<<<NGRP, 256, 0, stream>>>(x, s, y1);
  k_stats<<<192 * 64, 256, 0, stream>>>(y1, HID, SP1, 16, sum1, sq1);
  k_bnp<<<1, 192, 0, stream>>>(sum1, sq1, g1, b1, sc1, sh1, HID, 1.f / (NGRP * (float)SP1));
  k3_dw<<<NGRP, 256, 0, stream>>>(y1, s, sc1, sh1, y2);
  k_stats<<<192 * 64, 256, 0, stream>>>(y2, HID, SP2, 16, sum2, sq2);
  k_bnp<<<1, 192, 0, stream>>>(sum2, sq2, g2, b2, sc2, sh2, HID, 1.f / (NGRP * (float)SP2));
  k5_stage3<<<NGRP, 256, 0, stream>>>(y2, s, sc2, sh2, y3);
  k_stats<<<32 * 64, 256, 0, stream>>>(y3, 32, SP2, 16, sum3, sq3);
  k_bnp<<<1, 32, 0, stream>>>(sum3, sq3, g3, b3, sc3, sh3, 32, 1.f / (NGRP * (float)SP2));
  k7_out<<<8192, 256, 0, stream>>>(x, y3, sc3, sh3, out);
}

// Round 7
// 349.177 us; speedup vs baseline: 14.9341x; 1.0246x over previous
//
#include <hip/hip_runtime.h>
#include <hip/hip_bf16.h>

// HyperPatchInvertedResidual: per-patch hyper-conv pipeline with global BNs.
// b=16, c=32, H=W=128, 8x8 patches of 16x16 (+1 halo -> 18x18), HID=192.
// G = 16*64 = 1024 groups.

#define HID 192
#define SP1 324   // 18*18
#define SP2 256   // 16*16
#define HPAR 14016
#define R1 6144   // 32*192
#define R2 7872   // R1 + 192*9
#define NGRP 1024
#define PSTR 36   // patch LDS row stride (halves): conflict-free frag reads
#define WSTR 200  // w3 LDS row stride (halves)

typedef __hip_bfloat16 bf16;
typedef __attribute__((ext_vector_type(4))) unsigned short ushort4v;
typedef __attribute__((ext_vector_type(4))) short short4v;
typedef __attribute__((ext_vector_type(8))) short short8v;
typedef __attribute__((ext_vector_type(4))) float f32x4;
union Frag { short4v h[2]; short8v v; };

__device__ __forceinline__ float b2f(unsigned short u) {
  __hip_bfloat16_raw r; r.x = u;
  return __bfloat162float((bf16)r);
}
__device__ __forceinline__ unsigned short f2b(float f) {
  union { bf16 b; unsigned short u; } c;
  c.b = __float2bfloat16(f);
  return c.u;
}
// XCD-affinity remap: all 64 groups of one batch bi land on XCD bi%8.
__device__ __forceinline__ int remap_g(int blk) {
  int x = blk & 7, q = blk >> 3;
  return (((q >> 6) << 3) + x) * 64 + (q & 63);
}

// ---------------- K1: stage1 1x1 conv 32->192 via MFMA ----------------------
// y1[192,324] = w1[192,32] @ patch[32,324] per group.
// Operand roles swapped (patch tile first, like verified k5): D rows = sp ->
// each lane holds 4 consecutive sp -> direct short4 stores, no repack LDS,
// no wave barriers, no bank-conflicted LDS writes.
__global__ __launch_bounds__(256) void k1_stage1(
    const float* __restrict__ x, const float* __restrict__ s,
    bf16* __restrict__ y1) {
  int g = remap_g(blockIdx.x);
  int bi = g >> 6, fi = (g >> 3) & 7, fj = g & 7;
  __shared__ unsigned short wlds[6144];          // [o=192][ci=32]
  __shared__ unsigned short plds[336 * PSTR];    // [sp=336][ci], stride 36
  int tid = threadIdx.x;
  const float* sg = s + (size_t)bi * HPAR * 64 + fi * 8 + fj;
  for (int k = tid; k < 6144; k += 256) {
    int o = k >> 5, ci = k & 31;
    wlds[k] = f2b(sg[(size_t)(o * 32 + ci) * 64]);
  }
  const float* xb = x + (size_t)bi * 32 * 128 * 128;
  for (int idx = tid; idx < 32 * SP1; idx += 256) {
    int ci = idx / SP1, sp = idx - ci * SP1;
    int a = sp / 18, b = sp - a * 18;
    int r = fi * 16 + a - 1; r = r < 0 ? -r : (r > 127 ? 254 - r : r);
    int c = fj * 16 + b - 1; c = c < 0 ? -c : (c > 127 ? 254 - c : c);
    plds[sp * PSTR + ci] = f2b(xb[((size_t)ci * 128 + r) * 128 + c]);
  }
  for (int i = tid; i < 12 * PSTR; i += 256) plds[SP1 * PSTR + i] = 0;  // pad rows
  __syncthreads();

  int w = tid >> 6, l = tid & 63;
  int lj = l & 15, kg = l >> 4;
  // w1 o-frags resident in registers: 12 tiles x 4 VGPRs
  Frag wf[12];
#pragma unroll
  for (int ot = 0; ot < 12; ++ot) {
    const unsigned short* wp = wlds + (ot * 16 + lj) * 32 + 4 * kg;
    wf[ot].h[0] = *(const short4v*)wp;
    wf[ot].h[1] = *(const short4v*)(wp + 16);
  }
  unsigned short* yg = (unsigned short*)y1 + (size_t)g * HID * SP1;
#pragma unroll 1
  for (int sti = 0; sti < 6; ++sti) {
    int st = sti * 4 + w;          // interleaved: balances the 21-tile tail
    int sp0 = st * 16;
    if (sp0 >= SP1) continue;      // tiles 21..23 are pure pad
    const unsigned short* pb = plds + (sp0 + lj) * PSTR + 4 * kg;
    Frag tf;
    tf.h[0] = *(const short4v*)pb;
    tf.h[1] = *(const short4v*)(pb + 16);
    int spb = sp0 + kg * 4;
    bool stok = spb + 3 < SP1;     // tile 20: only kg=0 (sp 320..323) valid
#pragma unroll
    for (int ot = 0; ot < 12; ++ot) {
      f32x4 zz = {0.f, 0.f, 0.f, 0.f};
      f32x4 d = __builtin_amdgcn_mfma_f32_16x16x32_bf16(tf.v, wf[ot].v, zz, 0, 0, 0);
      if (stok) {
        short4v ov;
        ov.x = (short)f2b(d[0]); ov.y = (short)f2b(d[1]);
        ov.z = (short)f2b(d[2]); ov.w = (short)f2b(d[3]);
        *(short4v*)(yg + (size_t)(ot * 16 + lj) * SP1 + spb) = ov;
      }
    }
  }
}

// ---------------- stats: per-channel sum & sumsq over [G][CH][SPL] ----------
__global__ __launch_bounds__(256) void k_stats(
    const bf16* __restrict__ src, int CH, int SPL, int gPerBlk,
    float* __restrict__ sums, float* __restrict__ sqs) {
  int ch = blockIdx.x % CH;
  int g0 = (blockIdx.x / CH) * gPerBlk;
  int n4 = SPL >> 2;
  int wv = threadIdx.x >> 6, lane = threadIdx.x & 63;
  float s0 = 0.f, s1 = 0.f;
  for (int gg = wv; gg < gPerBlk; gg += 4) {
    const unsigned short* p =
        (const unsigned short*)(src + ((size_t)(g0 + gg) * CH + ch) * SPL);
    for (int j = lane; j < n4; j += 64) {
      ushort4v u = *(const ushort4v*)(p + 4 * j);
      float v0 = b2f(u.x), v1 = b2f(u.y), v2 = b2f(u.z), v3 = b2f(u.w);
      s0 += v0 + v1 + v2 + v3;
      s1 += v0 * v0 + v1 * v1 + v2 * v2 + v3 * v3;
    }
  }
#pragma unroll
  for (int off = 32; off; off >>= 1) {
    s0 += __shfl_down(s0, off);
    s1 += __shfl_down(s1, off);
  }
  __shared__ float red[8];
  if (lane == 0) { red[wv] = s0; red[4 + wv] = s1; }
  __syncthreads();
  if (threadIdx.x == 0) {
    float a = red[0] + red[1] + red[2] + red[3];
    float b = red[4] + red[5] + red[6] + red[7];
    atomicAdd(&sums[ch], a);
    atomicAdd(&sqs[ch], b);
  }
}

// ---------------- bn params: scale/shift from sums --------------------------
__global__ void k_bnp(const float* __restrict__ sums, const float* __restrict__ sqs,
                      const float* __restrict__ gamma, const float* __restrict__ beta,
                      float* __restrict__ sc, float* __restrict__ sh,
                      int CH, float invN) {
  int ch = threadIdx.x;
  if (ch >= CH) return;
  float m = sums[ch] * invN;
  float v = sqs[ch] * invN - m * m;
  float scale = gamma[ch] * rsqrtf(v + 1e-5f);
  sc[ch] = scale;
  sh[ch] = beta[ch] - m * scale;
}

// ---------------- K3: bn1+relu6 then 3x3 depthwise (valid) ------------------
// 8 channels/chunk, 24 chunks. Thread computes 2 units of (row, 4-col chunk):
// float4 LDS window reads (row stride 20), ushort4 vector stores.
__global__ __launch_bounds__(256) void k3_dw(
    const bf16* __restrict__ y1, const float* __restrict__ s,
    const float* __restrict__ sc1, const float* __restrict__ sh1,
    bf16* __restrict__ y2) {
  int g = remap_g(blockIdx.x);
  int bi = g >> 6, fi = (g >> 3) & 7, fj = g & 7;
  const float* sg2 = s + (size_t)bi * HPAR * 64 + fi * 8 + fj + (size_t)R1 * 64;
  __shared__ float tile[8 * 360];   // [c8][r*20 + c], 18 rows x 18 cols used
  __shared__ float w9s[72];
  int tid = threadIdx.x;
  int ch = tid >> 5, l = tid & 31;
  for (int cc = 0; cc < 24; ++cc) {
    if (cc) __syncthreads();
    for (int u = tid; u < 648; u += 256) {       // 8 ch x 81 ushort4
      int c8 = u / 81, j = u - c8 * 81;
      int o = cc * 8 + c8;
      ushort4v v = *(const ushort4v*)((const unsigned short*)y1 +
                                      ((size_t)g * HID + o) * SP1 + 4 * j);
      float scv = sc1[o], shv = sh1[o];
#pragma unroll
      for (int e = 0; e < 4; ++e) {
        int sp = 4 * j + e;
        int r = sp / 18, c = sp - r * 18;
        float vv = b2f(((const unsigned short*)&v)[e]) * scv + shv;
        tile[c8 * 360 + r * 20 + c] = fminf(fmaxf(vv, 0.f), 6.f);
      }
    }
    if (tid < 72) {
      int c8 = tid / 9, k = tid - c8 * 9;
      w9s[tid] = sg2[(size_t)((cc * 8 + c8) * 9 + k) * 64];
    }
    __syncthreads();
    int o = cc * 8 + ch;
    const float* tch = &tile[ch * 360];
    float wk[9];
#pragma unroll
    for (int k = 0; k < 9; ++k) wk[k] = w9s[ch * 9 + k];
    unsigned short* yrow = (unsigned short*)y2 + ((size_t)g * HID + o) * SP2;
#pragma unroll
    for (int k = 0; k < 2; ++k) {
      int u2 = l + 32 * k;
      int row = u2 >> 2, c4 = (u2 & 3) * 4;
      float a0 = 0.f, a1 = 0.f, a2 = 0.f, a3 = 0.f;
#pragma unroll
      for (int di = 0; di < 3; ++di) {
        const float* rp = tch + (row + di) * 20 + c4;
        float4 f = *(const float4*)rp;
        float f4 = rp[4], f5 = rp[5];
        float w0 = wk[di * 3], w1 = wk[di * 3 + 1], w2 = wk[di * 3 + 2];
        a0 += f.x * w0 + f.y * w1 + f.z * w2;
        a1 += f.y * w0 + f.z * w1 + f.w * w2;
        a2 += f.z * w0 + f.w * w1 + f4 * w2;
        a3 += f.w * w0 + f4 * w1 + f5 * w2;
      }
      ushort4v ov;
      ov.x = f2b(a0); ov.y = f2b(a1); ov.z = f2b(a2); ov.w = f2b(a3);
      *(ushort4v*)(yrow + row * 16 + c4) = ov;
    }
  }
}

// ---------------- K5: bn2+relu6 then 1x1 conv 192->32 via MFMA --------------
// y3[32,256] = W3[32,192] @ bn2relu6(y2)[192,256] per group.
// Operand roles swapped (T first) so D rows = sp -> direct short4 stores.
// Staging transpose [o][sp]->[sp][k] via 4x4 register-block transpose.
__global__ __launch_bounds__(256) void k5_stage3(
    const bf16* __restrict__ y2, const float* __restrict__ s,
    const float* __restrict__ sc2, const float* __restrict__ sh2,
    bf16* __restrict__ y3) {
  int g = remap_g(blockIdx.x);
  int bi = g >> 6, fi = (g >> 3) & 7, fj = g & 7;
  const float* sg = s + (size_t)bi * HPAR * 64 + fi * 8 + fj;
  __shared__ unsigned short bt[256 * PSTR];      // [sp=256][k-chunk=32], stride 36
  __shared__ unsigned short w3lds[32 * WSTR];    // [o2=32][k=192], stride 200
  int tid = threadIdx.x;
  // stage W3 (bf16) once: w3lds[o2][k] = s[R2 + o2*HID + k]
  {
    int o2 = tid >> 3, kb = (tid & 7) * 24;
    const float* wp = sg + (size_t)(R2 + o2 * HID + kb) * 64;
    for (int i = 0; i < 24; ++i)
      w3lds[o2 * WSTR + kb + i] = f2b(wp[(size_t)i * 64]);
  }
  int w = tid >> 6, l = tid & 63;
  int lj = l & 15, kg = l >> 4;
  f32x4 acc[4][2] = {};
  const unsigned short* y2g = (const unsigned short*)y2 + (size_t)g * HID * SP2;
#pragma unroll 1
  for (int kc = 0; kc < 6; ++kc) {
    if (kc) __syncthreads();   // protect bt from previous chunk's readers
    // stage bt[sp][kloc] for k in [kc*32, kc*32+32), bn2+relu6 fused,
    // 4x4 register transpose: 4 ushort4 loads along sp -> 4 ushort4 writes along k
#pragma unroll
    for (int uu = 0; uu < 2; ++uu) {
      int u = tid + 256 * uu;
      int tq = u & 7, spq = u >> 3;           // k-quad, sp-quad
      int o0 = kc * 32 + tq * 4;
      float4 scv = *(const float4*)(sc2 + o0);
      float4 shv = *(const float4*)(sh2 + o0);
      unsigned short hbuf[4][4];
#pragma unroll
      for (int e = 0; e < 4; ++e) {
        ushort4v v = *(const ushort4v*)(y2g + (size_t)(o0 + e) * SP2 + spq * 4);
        float sce = ((const float*)&scv)[e], she = ((const float*)&shv)[e];
#pragma unroll
        for (int j = 0; j < 4; ++j) {
          float f = b2f(((const unsigned short*)&v)[j]) * sce + she;
          hbuf[e][j] = f2b(fminf(fmaxf(f, 0.f), 6.f));
        }
      }
#pragma unroll
      for (int j = 0; j < 4; ++j) {
        ushort4v wv;
        wv.x = hbuf[0][j]; wv.y = hbuf[1][j]; wv.z = hbuf[2][j]; wv.w = hbuf[3][j];
        *(ushort4v*)(bt + (spq * 4 + j) * PSTR + tq * 4) = wv;
      }
    }
    __syncthreads();
    // W3 frags for this k-chunk (re-read from LDS each chunk: no runtime-
    // indexed frag arrays -> no scratch; 4 ds_read_b64 vs 8 MFMAs)
    Frag wf[2];
#pragma unroll
    for (int ot = 0; ot < 2; ++ot) {
      const unsigned short* wp = w3lds + (ot * 16 + lj) * WSTR + kc * 32 + 4 * kg;
      wf[ot].h[0] = *(const short4v*)wp;
      wf[ot].h[1] = *(const short4v*)(wp + 16);
    }
#pragma unroll
    for (int sti = 0; sti < 4; ++sti) {
      const unsigned short* pb = bt + ((w + 4 * sti) * 16 + lj) * PSTR + 4 * kg;
      Frag tf;
      tf.h[0] = *(const short4v*)pb;
      tf.h[1] = *(const short4v*)(pb + 16);
#pragma unroll
      for (int ot = 0; ot < 2; ++ot)
        acc[sti][ot] = __builtin_amdgcn_mfma_f32_16x16x32_bf16(
            tf.v, wf[ot].v, acc[sti][ot], 0, 0, 0);
    }
  }
  // D[m=kg*4+r][n=lj]: m indexes operand-1 (sp), n indexes operand-2 (o2)
  // -> lane holds 4 consecutive sp for one o2: direct short4 stores.
  unsigned short* yg3 = (unsigned short*)y3 + (size_t)g * 32 * SP2;
#pragma unroll
  for (int sti = 0; sti < 4; ++sti) {
    int spb = (w + 4 * sti) * 16 + kg * 4;
#pragma unroll
    for (int ot = 0; ot < 2; ++ot) {
      int o2 = ot * 16 + lj;
      short4v ov;
      ov.x = (short)f2b(acc[sti][ot][0]);
      ov.y = (short)f2b(acc[sti][ot][1]);
      ov.z = (short)f2b(acc[sti][ot][2]);
      ov.w = (short)f2b(acc[sti][ot][3]);
      *(short4v*)(yg3 + (size_t)o2 * SP2 + spb) = ov;
    }
  }
}

// ---------------- K7: bn3 + residual + scatter back (4 elems/thread) --------
__global__ __launch_bounds__(256) void k7_out(
    const float* __restrict__ x, const bf16* __restrict__ y3,
    const float* __restrict__ sc3, const float* __restrict__ sh3,
    float* __restrict__ out) {
  int idx = (blockIdx.x * 256 + threadIdx.x) * 4;  // 16*32*128*128 total
  int wcol = idx & 127;
  int hrow = (idx >> 7) & 127;
  int o2 = (idx >> 14) & 31;
  int bi = idx >> 19;
  int g = bi * 64 + (hrow >> 4) * 8 + (wcol >> 4);
  ushort4v u = *(const ushort4v*)((const unsigned short*)y3 +
                                  ((size_t)g * 32 + o2) * SP2 +
                                  ((hrow & 15) << 4) + (wcol & 15));
  float4 xv = *(const float4*)(x + idx);
  float sc = sc3[o2], sh = sh3[o2];
  float4 ov;
  ov.x = xv.x + b2f(u.x) * sc + sh;
  ov.y = xv.y + b2f(u.y) * sc + sh;
  ov.z = xv.z + b2f(u.z) * sc + sh;
  ov.w = xv.w + b2f(u.w) * sc + sh;
  *(float4*)(out + idx) = ov;
}

extern "C" void kernel_launch(void* const* d_in, const int* in_sizes, int n_in,
                              void* d_out, int out_size, void* d_ws, size_t ws_size,
                              hipStream_t stream) {
  const float* x  = (const float*)d_in[0];
  const float* s  = (const float*)d_in[1];
  const float* g1 = (const float*)d_in[2];
  const float* b1 = (const float*)d_in[3];
  const float* g2 = (const float*)d_in[4];
  const float* b2 = (const float*)d_in[5];
  const float* g3 = (const float*)d_in[6];
  const float* b3 = (const float*)d_in[7];
  float* out = (float*)d_out;

  char* ws = (char*)d_ws;
  float* stats = (float*)ws;
  float* sum1 = stats;        float* sq1 = stats + 192;
  float* sum2 = stats + 384;  float* sq2 = stats + 576;
  float* sum3 = stats + 768;  float* sq3 = stats + 800;
  float* sc1 = stats + 1024;  float* sh1 = stats + 1216;
  float* sc2 = stats + 1408;  float* sh2 = stats + 1600;
  float* sc3 = stats + 1792;  float* sh3 = stats + 1824;
  bf16* y1 = (bf16*)(ws + 8192);                       // 1024*192*324 bf16
  bf16* y2 = y1 + (size_t)NGRP * HID * SP1;            // 1024*192*256 bf16
  bf16* y3 = y1;                                       // alias: y1 dead by K5

  hipMemsetAsync(stats, 0, 832 * sizeof(float), stream);

  k1_stage1<<<NGRP, 256, 0, stream>>>(x, s, y1);
  k_stats<<<192 * 64, 256, 0, stream>>>(y1, HID, SP1, 16, sum1, sq1);
  k_bnp<<<1, 192, 0, stream>>>(sum1, sq1, g1, b1, sc1, sh1, HID, 1.f / (NGRP * (float)SP1));
  k3_dw<<<NGRP, 256, 0, stream>>>(y1, s, sc1, sh1, y2);
  k_stats<<<192 * 64, 256, 0, stream>>>(y2, HID, SP2, 16, sum2, sq2);
  k_bnp<<<1, 192, 0, stream>>>(sum2, sq2, g2, b2, sc2, sh2, HID, 1.f / (NGRP * (float)SP2));
  k5_stage3<<<NGRP, 256, 0, stream>>>(y2, s, sc2, sh2, y3);
  k_stats<<<32 * 64, 256, 0, stream>>>(y3, 32, SP2, 16, sum3, sq3);
  k_bnp<<<1, 32, 0, stream>>>(sum3, sq3, g3, b3, sc3, sh3, 32, 1.f / (NGRP * (float)SP2));
  k7_out<<<8192, 256, 0, stream>>>(x, y3, sc3, sh3, out);
}

// Round 8
// 319.503 us; speedup vs baseline: 16.3210x; 1.0929x over previous
//
#include <hip/hip_runtime.h>
#include <hip/hip_bf16.h>

// HyperPatchInvertedResidual: per-patch hyper-conv pipeline with global BNs.
// b=16, c=32, H=W=128, 8x8 patches of 16x16 (+1 halo -> 18x18), HID=192.
// G = 16*64 = 1024 groups.

#define HID 192
#define SP1 324   // 18*18
#define SP2 256   // 16*16
#define HPAR 14016
#define R1 6144   // 32*192
#define R2 7872   // R1 + 192*9
#define NGRP 1024
#define PSTR 36   // patch LDS row stride (halves): conflict-free frag reads
#define WSTR 200  // w3 LDS row stride (halves)

typedef __hip_bfloat16 bf16;
typedef __attribute__((ext_vector_type(4))) unsigned short ushort4v;
typedef __attribute__((ext_vector_type(2))) unsigned short ushort2v;  // 4B
typedef __attribute__((ext_vector_type(4))) short short4v;
typedef __attribute__((ext_vector_type(8))) short short8v;
typedef __attribute__((ext_vector_type(4))) float f32x4;
union Frag { short4v h[2]; short8v v; };

__device__ __forceinline__ float b2f(unsigned short u) {
  __hip_bfloat16_raw r; r.x = u;
  return __bfloat162float((bf16)r);
}
__device__ __forceinline__ unsigned short f2b(float f) {
  union { bf16 b; unsigned short u; } c;
  c.b = __float2bfloat16(f);
  return c.u;
}
// XCD-affinity remap: all 64 groups of one batch bi land on XCD bi%8.
__device__ __forceinline__ int remap_g(int blk) {
  int x = blk & 7, q = blk >> 3;
  return (((q >> 6) << 3) + x) * 64 + (q & 63);
}

// ---------------- K1: stage1 1x1 conv 32->192 via MFMA ----------------------
// y1[192,324] = w1[192,32] @ patch[32,324] per group.
// Operand roles swapped (patch tile first, like verified k5): D rows = sp ->
// each lane holds 4 consecutive sp -> direct short4 stores, no repack LDS,
// no wave barriers, no bank-conflicted LDS writes.
__global__ __launch_bounds__(256) void k1_stage1(
    const float* __restrict__ x, const float* __restrict__ s,
    bf16* __restrict__ y1) {
  int g = remap_g(blockIdx.x);
  int bi = g >> 6, fi = (g >> 3) & 7, fj = g & 7;
  __shared__ unsigned short wlds[6144];          // [o=192][ci=32]
  __shared__ unsigned short plds[336 * PSTR];    // [sp=336][ci], stride 36
  int tid = threadIdx.x;
  const float* sg = s + (size_t)bi * HPAR * 64 + fi * 8 + fj;
  for (int k = tid; k < 6144; k += 256) {
    int o = k >> 5, ci = k & 31;
    wlds[k] = f2b(sg[(size_t)(o * 32 + ci) * 64]);
  }
  const float* xb = x + (size_t)bi * 32 * 128 * 128;
  for (int idx = tid; idx < 32 * SP1; idx += 256) {
    int ci = idx / SP1, sp = idx - ci * SP1;
    int a = sp / 18, b = sp - a * 18;
    int r = fi * 16 + a - 1; r = r < 0 ? -r : (r > 127 ? 254 - r : r);
    int c = fj * 16 + b - 1; c = c < 0 ? -c : (c > 127 ? 254 - c : c);
    plds[sp * PSTR + ci] = f2b(xb[((size_t)ci * 128 + r) * 128 + c]);
  }
  for (int i = tid; i < 12 * PSTR; i += 256) plds[SP1 * PSTR + i] = 0;  // pad rows
  __syncthreads();

  int w = tid >> 6, l = tid & 63;
  int lj = l & 15, kg = l >> 4;
  // w1 o-frags resident in registers: 12 tiles x 4 VGPRs
  Frag wf[12];
#pragma unroll
  for (int ot = 0; ot < 12; ++ot) {
    const unsigned short* wp = wlds + (ot * 16 + lj) * 32 + 4 * kg;
    wf[ot].h[0] = *(const short4v*)wp;
    wf[ot].h[1] = *(const short4v*)(wp + 16);
  }
  unsigned short* yg = (unsigned short*)y1 + (size_t)g * HID * SP1;
#pragma unroll 1
  for (int sti = 0; sti < 6; ++sti) {
    int st = sti * 4 + w;          // interleaved: balances the 21-tile tail
    int sp0 = st * 16;
    if (sp0 >= SP1) continue;      // tiles 21..23 are pure pad
    const unsigned short* pb = plds + (sp0 + lj) * PSTR + 4 * kg;
    Frag tf;
    tf.h[0] = *(const short4v*)pb;
    tf.h[1] = *(const short4v*)(pb + 16);
    int spb = sp0 + kg * 4;
    bool stok = spb + 3 < SP1;     // tile 20: only kg=0 (sp 320..323) valid
#pragma unroll
    for (int ot = 0; ot < 12; ++ot) {
      f32x4 zz = {0.f, 0.f, 0.f, 0.f};
      f32x4 d = __builtin_amdgcn_mfma_f32_16x16x32_bf16(tf.v, wf[ot].v, zz, 0, 0, 0);
      if (stok) {
        short4v ov;
        ov.x = (short)f2b(d[0]); ov.y = (short)f2b(d[1]);
        ov.z = (short)f2b(d[2]); ov.w = (short)f2b(d[3]);
        *(short4v*)(yg + (size_t)(ot * 16 + lj) * SP1 + spb) = ov;
      }
    }
  }
}

// ---------------- stats: per-channel sum & sumsq over [G][CH][SPL] ----------
__global__ __launch_bounds__(256) void k_stats(
    const bf16* __restrict__ src, int CH, int SPL, int gPerBlk,
    float* __restrict__ sums, float* __restrict__ sqs) {
  int ch = blockIdx.x % CH;
  int g0 = (blockIdx.x / CH) * gPerBlk;
  int n4 = SPL >> 2;
  int wv = threadIdx.x >> 6, lane = threadIdx.x & 63;
  float s0 = 0.f, s1 = 0.f;
  for (int gg = wv; gg < gPerBlk; gg += 4) {
    const unsigned short* p =
        (const unsigned short*)(src + ((size_t)(g0 + gg) * CH + ch) * SPL);
    for (int j = lane; j < n4; j += 64) {
      ushort4v u = *(const ushort4v*)(p + 4 * j);
      float v0 = b2f(u.x), v1 = b2f(u.y), v2 = b2f(u.z), v3 = b2f(u.w);
      s0 += v0 + v1 + v2 + v3;
      s1 += v0 * v0 + v1 * v1 + v2 * v2 + v3 * v3;
    }
  }
#pragma unroll
  for (int off = 32; off; off >>= 1) {
    s0 += __shfl_down(s0, off);
    s1 += __shfl_down(s1, off);
  }
  __shared__ float red[8];
  if (lane == 0) { red[wv] = s0; red[4 + wv] = s1; }
  __syncthreads();
  if (threadIdx.x == 0) {
    float a = red[0] + red[1] + red[2] + red[3];
    float b = red[4] + red[5] + red[6] + red[7];
    atomicAdd(&sums[ch], a);
    atomicAdd(&sqs[ch], b);
  }
}

// ---------------- bn params: scale/shift from sums --------------------------
__global__ void k_bnp(const float* __restrict__ sums, const float* __restrict__ sqs,
                      const float* __restrict__ gamma, const float* __restrict__ beta,
                      float* __restrict__ sc, float* __restrict__ sh,
                      int CH, float invN) {
  int ch = threadIdx.x;
  if (ch >= CH) return;
  float m = sums[ch] * invN;
  float v = sqs[ch] * invN - m * m;
  float scale = gamma[ch] * rsqrtf(v + 1e-5f);
  sc[ch] = scale;
  sh[ch] = beta[ch] - m * scale;
}

// ---------------- K3: bn1+relu6 then 3x3 depthwise (valid) ------------------
// LDS-free rewrite: thread-task = (channel, 4-col quad, all 16 out rows).
// Streams 18 input rows via 3 x dword loads (4B-aligned), bn1+relu6 in regs,
// 3-slot out-row ring with static indices (full unroll). Zero barriers.
__global__ __launch_bounds__(256) void k3_dw(
    const bf16* __restrict__ y1, const float* __restrict__ s,
    const float* __restrict__ sc1, const float* __restrict__ sh1,
    bf16* __restrict__ y2) {
  int g = remap_g(blockIdx.x);
  int bi = g >> 6, fi = (g >> 3) & 7, fj = g & 7;
  const float* sg2 = s + (size_t)bi * HPAR * 64 + fi * 8 + fj + (size_t)R1 * 64;
  const unsigned short* y1g = (const unsigned short*)y1 + (size_t)g * HID * SP1;
  unsigned short* y2g = (unsigned short*)y2 + (size_t)g * HID * SP2;
  int tid = threadIdx.x;
#pragma unroll 1
  for (int p = 0; p < 3; ++p) {
    int tau = tid + 256 * p;            // 0..767
    int ch = tau >> 2, c4 = (tau & 3) * 4;
    float scv = sc1[ch], shv = sh1[ch];
    float wk[9];
#pragma unroll
    for (int k = 0; k < 9; ++k) wk[k] = sg2[(size_t)(ch * 9 + k) * 64];
    const unsigned short* rp = y1g + ch * SP1 + c4;
    unsigned short* op = y2g + ch * SP2 + c4;
    float accR[3][4];
#pragma unroll
    for (int ir = 0; ir < 18; ++ir) {
      // input cols c4..c4+5 of row ir: three 4B loads (8B vectors would be
      // misaligned on odd rows: 18 halves = 36B row stride)
      ushort2v q0 = *(const ushort2v*)(rp + ir * 18);
      ushort2v q1 = *(const ushort2v*)(rp + ir * 18 + 2);
      ushort2v q2 = *(const ushort2v*)(rp + ir * 18 + 4);
      float w6[6];
      w6[0] = fminf(fmaxf(b2f(q0.x) * scv + shv, 0.f), 6.f);
      w6[1] = fminf(fmaxf(b2f(q0.y) * scv + shv, 0.f), 6.f);
      w6[2] = fminf(fmaxf(b2f(q1.x) * scv + shv, 0.f), 6.f);
      w6[3] = fminf(fmaxf(b2f(q1.y) * scv + shv, 0.f), 6.f);
      w6[4] = fminf(fmaxf(b2f(q2.x) * scv + shv, 0.f), 6.f);
      w6[5] = fminf(fmaxf(b2f(q2.y) * scv + shv, 0.f), 6.f);
#pragma unroll
      for (int k = 0; k < 3; ++k) {     // in row ir feeds out row ir-k (tap k)
        int orow = ir - k;
        if (orow < 0 || orow >= 16) continue;
        float* A = accR[orow % 3];      // static under full unroll
#pragma unroll
        for (int j = 0; j < 4; ++j) {
          float t = w6[j] * wk[3 * k] + w6[j + 1] * wk[3 * k + 1] +
                    w6[j + 2] * wk[3 * k + 2];
          A[j] = (k == 0) ? t : A[j] + t;
        }
        if (k == 2) {
          ushort4v ov;
          ov.x = f2b(A[0]); ov.y = f2b(A[1]);
          ov.z = f2b(A[2]); ov.w = f2b(A[3]);
          *(ushort4v*)(op + orow * 16) = ov;   // 8B-aligned: 32B row stride
        }
      }
    }
  }
}

// ---------------- K5: bn2+relu6 then 1x1 conv 192->32 via MFMA --------------
// y3[32,256] = W3[32,192] @ bn2relu6(y2)[192,256] per group.
// Operand roles swapped (T first) so D rows = sp -> direct short4 stores.
// Staging transpose [o][sp]->[sp][k] via 4x4 register-block transpose.
__global__ __launch_bounds__(256) void k5_stage3(
    const bf16* __restrict__ y2, const float* __restrict__ s,
    const float* __restrict__ sc2, const float* __restrict__ sh2,
    bf16* __restrict__ y3) {
  int g = remap_g(blockIdx.x);
  int bi = g >> 6, fi = (g >> 3) & 7, fj = g & 7;
  const float* sg = s + (size_t)bi * HPAR * 64 + fi * 8 + fj;
  __shared__ unsigned short bt[256 * PSTR];      // [sp=256][k-chunk=32], stride 36
  __shared__ unsigned short w3lds[32 * WSTR];    // [o2=32][k=192], stride 200
  int tid = threadIdx.x;
  // stage W3 (bf16) once: w3lds[o2][k] = s[R2 + o2*HID + k]
  {
    int o2 = tid >> 3, kb = (tid & 7) * 24;
    const float* wp = sg + (size_t)(R2 + o2 * HID + kb) * 64;
    for (int i = 0; i < 24; ++i)
      w3lds[o2 * WSTR + kb + i] = f2b(wp[(size_t)i * 64]);
  }
  int w = tid >> 6, l = tid & 63;
  int lj = l & 15, kg = l >> 4;
  f32x4 acc[4][2] = {};
  const unsigned short* y2g = (const unsigned short*)y2 + (size_t)g * HID * SP2;
#pragma unroll 1
  for (int kc = 0; kc < 6; ++kc) {
    if (kc) __syncthreads();   // protect bt from previous chunk's readers
    // stage bt[sp][kloc] for k in [kc*32, kc*32+32), bn2+relu6 fused,
    // 4x4 register transpose: 4 ushort4 loads along sp -> 4 ushort4 writes along k
#pragma unroll
    for (int uu = 0; uu < 2; ++uu) {
      int u = tid + 256 * uu;
      int tq = u & 7, spq = u >> 3;           // k-quad, sp-quad
      int o0 = kc * 32 + tq * 4;
      float4 scv = *(const float4*)(sc2 + o0);
      float4 shv = *(const float4*)(sh2 + o0);
      unsigned short hbuf[4][4];
#pragma unroll
      for (int e = 0; e < 4; ++e) {
        ushort4v v = *(const ushort4v*)(y2g + (size_t)(o0 + e) * SP2 + spq * 4);
        float sce = ((const float*)&scv)[e], she = ((const float*)&shv)[e];
#pragma unroll
        for (int j = 0; j < 4; ++j) {
          float f = b2f(((const unsigned short*)&v)[j]) * sce + she;
          hbuf[e][j] = f2b(fminf(fmaxf(f, 0.f), 6.f));
        }
      }
#pragma unroll
      for (int j = 0; j < 4; ++j) {
        ushort4v wv;
        wv.x = hbuf[0][j]; wv.y = hbuf[1][j]; wv.z = hbuf[2][j]; wv.w = hbuf[3][j];
        *(ushort4v*)(bt + (spq * 4 + j) * PSTR + tq * 4) = wv;
      }
    }
    __syncthreads();
    // W3 frags for this k-chunk (re-read from LDS each chunk: no runtime-
    // indexed frag arrays -> no scratch; 4 ds_read_b64 vs 8 MFMAs)
    Frag wf[2];
#pragma unroll
    for (int ot = 0; ot < 2; ++ot) {
      const unsigned short* wp = w3lds + (ot * 16 + lj) * WSTR + kc * 32 + 4 * kg;
      wf[ot].h[0] = *(const short4v*)wp;
      wf[ot].h[1] = *(const short4v*)(wp + 16);
    }
#pragma unroll
    for (int sti = 0; sti < 4; ++sti) {
      const unsigned short* pb = bt + ((w + 4 * sti) * 16 + lj) * PSTR + 4 * kg;
      Frag tf;
      tf.h[0] = *(const short4v*)pb;
      tf.h[1] = *(const short4v*)(pb + 16);
#pragma unroll
      for (int ot = 0; ot < 2; ++ot)
        acc[sti][ot] = __builtin_amdgcn_mfma_f32_16x16x32_bf16(
            tf.v, wf[ot].v, acc[sti][ot], 0, 0, 0);
    }
  }
  // D[m=kg*4+r][n=lj]: m indexes operand-1 (sp), n indexes operand-2 (o2)
  // -> lane holds 4 consecutive sp for one o2: direct short4 stores.
  unsigned short* yg3 = (unsigned short*)y3 + (size_t)g * 32 * SP2;
#pragma unroll
  for (int sti = 0; sti < 4; ++sti) {
    int spb = (w + 4 * sti) * 16 + kg * 4;
#pragma unroll
    for (int ot = 0; ot < 2; ++ot) {
      int o2 = ot * 16 + lj;
      short4v ov;
      ov.x = (short)f2b(acc[sti][ot][0]);
      ov.y = (short)f2b(acc[sti][ot][1]);
      ov.z = (short)f2b(acc[sti][ot][2]);
      ov.w = (short)f2b(acc[sti][ot][3]);
      *(short4v*)(yg3 + (size_t)o2 * SP2 + spb) = ov;
    }
  }
}

// ---------------- K7: bn3 + residual + scatter back (4 elems/thread) --------
__global__ __launch_bounds__(256) void k7_out(
    const float* __restrict__ x, const bf16* __restrict__ y3,
    const float* __restrict__ sc3, const float* __restrict__ sh3,
    float* __restrict__ out) {
  int idx = (blockIdx.x * 256 + threadIdx.x) * 4;  // 16*32*128*128 total
  int wcol = idx & 127;
  int hrow = (idx >> 7) & 127;
  int o2 = (idx >> 14) & 31;
  int bi = idx >> 19;
  int g = bi * 64 + (hrow >> 4) * 8 + (wcol >> 4);
  ushort4v u = *(const ushort4v*)((const unsigned short*)y3 +
                                  ((size_t)g * 32 + o2) * SP2 +
                                  ((hrow & 15) << 4) + (wcol & 15));
  float4 xv = *(const float4*)(x + idx);
  float sc = sc3[o2], sh = sh3[o2];
  float4 ov;
  ov.x = xv.x + b2f(u.x) * sc + sh;
  ov.y = xv.y + b2f(u.y) * sc + sh;
  ov.z = xv.z + b2f(u.z) * sc + sh;
  ov.w = xv.w + b2f(u.w) * sc + sh;
  *(float4*)(out + idx) = ov;
}

extern "C" void kernel_launch(void* const* d_in, const int* in_sizes, int n_in,
                              void* d_out, int out_size, void* d_ws, size_t ws_size,
                              hipStream_t stream) {
  const float* x  = (const float*)d_in[0];
  const float* s  = (const float*)d_in[1];
  const float* g1 = (const float*)d_in[2];
  const float* b1 = (const float*)d_in[3];
  const float* g2 = (const float*)d_in[4];
  const float* b2 = (const float*)d_in[5];
  const float* g3 = (const float*)d_in[6];
  const float* b3 = (const float*)d_in[7];
  float* out = (float*)d_out;

  char* ws = (char*)d_ws;
  float* stats = (float*)ws;
  float* sum1 = stats;        float* sq1 = stats + 192;
  float* sum2 = stats + 384;  float* sq2 = stats + 576;
  float* sum3 = stats + 768;  float* sq3 = stats + 800;
  float* sc1 = stats + 1024;  float* sh1 = stats + 1216;
  float* sc2 = stats + 1408;  float* sh2 = stats + 1600;
  float* sc3 = stats + 1792;  float* sh3 = stats + 1824;
  bf16* y1 = (bf16*)(ws + 8192);                       // 1024*192*324 bf16
  bf16* y2 = y1 + (size_t)NGRP * HID * SP1;            // 1024*192*256 bf16
  bf16* y3 = y1;                                       // alias: y1 dead by K5

  hipMemsetAsync(stats, 0, 832 * sizeof(float), stream);

  k1_stage1<<<NGRP, 256, 0, stream>>>(x, s, y1);
  k_stats<<<192 * 64, 256, 0, stream>>>(y1, HID, SP1, 16, sum1, sq1);
  k_bnp<<<1, 192, 0, stream>>>(sum1, sq1, g1, b1, sc1, sh1, HID, 1.f / (NGRP * (float)SP1));
  k3_dw<<<NGRP, 256, 0, stream>>>(y1, s, sc1, sh1, y2);
  k_stats<<<192 * 64, 256, 0, stream>>>(y2, HID, SP2, 16, sum2, sq2);
  k_bnp<<<1, 192, 0, stream>>>(sum2, sq2, g2, b2, sc2, sh2, HID, 1.f / (NGRP * (float)SP2));
  k5_stage3<<<NGRP, 256, 0, stream>>>(y2, s, sc2, sh2, y3);
  k_stats<<<32 * 64, 256, 0, stream>>>(y3, 32, SP2, 16, sum3, sq3);
  k_bnp<<<1, 32, 0, stream>>>(sum3, sq3, g3, b3, sc3, sh3, 32, 1.f / (NGRP * (float)SP2));
  k7_out<<<8192, 256, 0, stream>>>(x, y3, sc3, sh3, out);
}

// Round 9
// 295.110 us; speedup vs baseline: 17.6701x; 1.0827x over previous
//
#include <hip/hip_runtime.h>
#include <hip/hip_bf16.h>

// HyperPatchInvertedResidual: per-patch hyper-conv pipeline with global BNs.
// b=16, c=32, H=W=128, 8x8 patches of 16x16 (+1 halo -> 18x18), HID=192.
// G = 16*64 = 1024 groups.

#define HID 192
#define SP1 324   // 18*18
#define SP2 256   // 16*16
#define HPAR 14016
#define R1 6144   // 32*192
#define R2 7872   // R1 + 192*9
#define NGRP 1024
#define PSTR 36   // patch LDS row stride (halves): conflict-free frag reads

typedef __hip_bfloat16 bf16;
typedef __attribute__((ext_vector_type(4))) unsigned short ushort4v;
typedef __attribute__((ext_vector_type(2))) unsigned short ushort2v;  // 4B
typedef __attribute__((ext_vector_type(4))) short short4v;
typedef __attribute__((ext_vector_type(8))) short short8v;
typedef __attribute__((ext_vector_type(4))) float f32x4;
union Frag { short4v h[2]; short8v v; };

__device__ __forceinline__ float b2f(unsigned short u) {
  __hip_bfloat16_raw r; r.x = u;
  return __bfloat162float((bf16)r);
}
__device__ __forceinline__ unsigned short f2b(float f) {
  union { bf16 b; unsigned short u; } c;
  c.b = __float2bfloat16(f);
  return c.u;
}
// XCD-affinity remap: all 64 groups of one batch bi land on XCD bi%8.
__device__ __forceinline__ int remap_g(int blk) {
  int x = blk & 7, q = blk >> 3;
  return (((q >> 6) << 3) + x) * 64 + (q & 63);
}

// ---------------- K0: hyper-weight gather/transpose -------------------------
// s[bi][hp][8][8] f32 (stride-64 per-group gather) -> wt[g][hp] bf16, dense.
// Kills the 6144-scalar-load stride-256B latency gather in k1/k3/k5.
__global__ __launch_bounds__(256) void k0_wt(
    const float* __restrict__ s, unsigned short* __restrict__ wt) {
  int blk = blockIdx.x;             // 16 bi x 219 chunks of 64 hp
  int bi = blk / 219, ck = blk - bi * 219;
  int hp0 = ck * 64;
  __shared__ float t[64][65];
  int tid = threadIdx.x;
  int lw = tid >> 6, l = tid & 63;
  const float* sp = s + ((size_t)bi * HPAR + hp0) * 64;
#pragma unroll
  for (int i = 0; i < 16; ++i) {
    int row = lw * 16 + i;
    t[row][l] = sp[(size_t)row * 64 + l];
  }
  __syncthreads();
  int g = lw * 16 + (l >> 2), seg = l & 3;    // 64 g x 4 segs of 16 hp
  unsigned short* wp = wt + ((size_t)(bi * 64 + g)) * HPAR + hp0 + seg * 16;
#pragma unroll
  for (int q = 0; q < 4; ++q) {
    ushort4v ov;
    ov.x = f2b(t[seg * 16 + q * 4 + 0][g]);
    ov.y = f2b(t[seg * 16 + q * 4 + 1][g]);
    ov.z = f2b(t[seg * 16 + q * 4 + 2][g]);
    ov.w = f2b(t[seg * 16 + q * 4 + 3][g]);
    *(ushort4v*)(wp + q * 4) = ov;
  }
}

// ---------------- K1: stage1 1x1 conv 32->192 via MFMA ----------------------
// y1[192,324] = w1[192,32] @ patch[32,324] per group. Weights come dense from
// wt (no LDS staging, no gather): 24 x 8B L3-resident loads per lane.
__global__ __launch_bounds__(256) void k1_stage1(
    const float* __restrict__ x, const unsigned short* __restrict__ wt,
    bf16* __restrict__ y1) {
  int g = remap_g(blockIdx.x);
  int bi = g >> 6, fi = (g >> 3) & 7, fj = g & 7;
  __shared__ unsigned short plds[336 * PSTR];    // [sp=336][ci], stride 36
  int tid = threadIdx.x;
  int w = tid >> 6, l = tid & 63;
  int lj = l & 15, kg = l >> 4;
  // w1 o-frags straight from wt[g][o*32+ci]: 12 tiles x 4 VGPRs
  const unsigned short* w1g = wt + (size_t)g * HPAR;
  Frag wf[12];
#pragma unroll
  for (int ot = 0; ot < 12; ++ot) {
    const unsigned short* wp = w1g + (ot * 16 + lj) * 32 + 4 * kg;
    wf[ot].h[0] = *(const short4v*)wp;
    wf[ot].h[1] = *(const short4v*)(wp + 16);
  }
  const float* xb = x + (size_t)bi * 32 * 128 * 128;
  for (int idx = tid; idx < 32 * SP1; idx += 256) {
    int ci = idx / SP1, sp = idx - ci * SP1;
    int a = sp / 18, b = sp - a * 18;
    int r = fi * 16 + a - 1; r = r < 0 ? -r : (r > 127 ? 254 - r : r);
    int c = fj * 16 + b - 1; c = c < 0 ? -c : (c > 127 ? 254 - c : c);
    plds[sp * PSTR + ci] = f2b(xb[((size_t)ci * 128 + r) * 128 + c]);
  }
  for (int i = tid; i < 12 * PSTR; i += 256) plds[SP1 * PSTR + i] = 0;  // pad rows
  __syncthreads();

  unsigned short* yg = (unsigned short*)y1 + (size_t)g * HID * SP1;
#pragma unroll 1
  for (int sti = 0; sti < 6; ++sti) {
    int st = sti * 4 + w;          // interleaved: balances the 21-tile tail
    int sp0 = st * 16;
    if (sp0 >= SP1) continue;      // tiles 21..23 are pure pad
    const unsigned short* pb = plds + (sp0 + lj) * PSTR + 4 * kg;
    Frag tf;
    tf.h[0] = *(const short4v*)pb;
    tf.h[1] = *(const short4v*)(pb + 16);
    int spb = sp0 + kg * 4;
    bool stok = spb + 3 < SP1;     // tile 20: only kg=0 (sp 320..323) valid
#pragma unroll
    for (int ot = 0; ot < 12; ++ot) {
      f32x4 zz = {0.f, 0.f, 0.f, 0.f};
      f32x4 d = __builtin_amdgcn_mfma_f32_16x16x32_bf16(tf.v, wf[ot].v, zz, 0, 0, 0);
      if (stok) {
        short4v ov;
        ov.x = (short)f2b(d[0]); ov.y = (short)f2b(d[1]);
        ov.z = (short)f2b(d[2]); ov.w = (short)f2b(d[3]);
        *(short4v*)(yg + (size_t)(ot * 16 + lj) * SP1 + spb) = ov;
      }
    }
  }
}

// ---------------- stats: per-channel sum & sumsq over [G][CH][SPL] ----------
__global__ __launch_bounds__(256) void k_stats(
    const bf16* __restrict__ src, int CH, int SPL, int gPerBlk,
    float* __restrict__ sums, float* __restrict__ sqs) {
  int ch = blockIdx.x % CH;
  int g0 = (blockIdx.x / CH) * gPerBlk;
  int n4 = SPL >> 2;
  int wv = threadIdx.x >> 6, lane = threadIdx.x & 63;
  float s0 = 0.f, s1 = 0.f;
  for (int gg = wv; gg < gPerBlk; gg += 4) {
    const unsigned short* p =
        (const unsigned short*)(src + ((size_t)(g0 + gg) * CH + ch) * SPL);
    for (int j = lane; j < n4; j += 64) {
      ushort4v u = *(const ushort4v*)(p + 4 * j);
      float v0 = b2f(u.x), v1 = b2f(u.y), v2 = b2f(u.z), v3 = b2f(u.w);
      s0 += v0 + v1 + v2 + v3;
      s1 += v0 * v0 + v1 * v1 + v2 * v2 + v3 * v3;
    }
  }
#pragma unroll
  for (int off = 32; off; off >>= 1) {
    s0 += __shfl_down(s0, off);
    s1 += __shfl_down(s1, off);
  }
  __shared__ float red[8];
  if (lane == 0) { red[wv] = s0; red[4 + wv] = s1; }
  __syncthreads();
  if (threadIdx.x == 0) {
    float a = red[0] + red[1] + red[2] + red[3];
    float b = red[4] + red[5] + red[6] + red[7];
    atomicAdd(&sums[ch], a);
    atomicAdd(&sqs[ch], b);
  }
}

// ---------------- bn params: scale/shift from sums --------------------------
__global__ void k_bnp(const float* __restrict__ sums, const float* __restrict__ sqs,
                      const float* __restrict__ gamma, const float* __restrict__ beta,
                      float* __restrict__ sc, float* __restrict__ sh,
                      int CH, float invN) {
  int ch = threadIdx.x;
  if (ch >= CH) return;
  float m = sums[ch] * invN;
  float v = sqs[ch] * invN - m * m;
  float scale = gamma[ch] * rsqrtf(v + 1e-5f);
  sc[ch] = scale;
  sh[ch] = beta[ch] - m * scale;
}

// ---------------- K3: bn1+relu6 then 3x3 depthwise (valid) ------------------
// LDS-free: thread-task = (channel, 4-col quad, all 16 out rows). Streams 18
// input rows via 3 x dword loads, 3-slot out-row ring, zero barriers.
__global__ __launch_bounds__(256) void k3_dw(
    const bf16* __restrict__ y1, const unsigned short* __restrict__ wt,
    const float* __restrict__ sc1, const float* __restrict__ sh1,
    bf16* __restrict__ y2) {
  int g = remap_g(blockIdx.x);
  const unsigned short* w2g = wt + (size_t)g * HPAR + R1;
  const unsigned short* y1g = (const unsigned short*)y1 + (size_t)g * HID * SP1;
  unsigned short* y2g = (unsigned short*)y2 + (size_t)g * HID * SP2;
  int tid = threadIdx.x;
#pragma unroll 1
  for (int p = 0; p < 3; ++p) {
    int tau = tid + 256 * p;            // 0..767
    int ch = tau >> 2, c4 = (tau & 3) * 4;
    float scv = sc1[ch], shv = sh1[ch];
    float wk[9];
#pragma unroll
    for (int k = 0; k < 9; ++k) wk[k] = b2f(w2g[ch * 9 + k]);
    const unsigned short* rp = y1g + ch * SP1 + c4;
    unsigned short* op = y2g + ch * SP2 + c4;
    float accR[3][4];
#pragma unroll
    for (int ir = 0; ir < 18; ++ir) {
      ushort2v q0 = *(const ushort2v*)(rp + ir * 18);
      ushort2v q1 = *(const ushort2v*)(rp + ir * 18 + 2);
      ushort2v q2 = *(const ushort2v*)(rp + ir * 18 + 4);
      float w6[6];
      w6[0] = fminf(fmaxf(b2f(q0.x) * scv + shv, 0.f), 6.f);
      w6[1] = fminf(fmaxf(b2f(q0.y) * scv + shv, 0.f), 6.f);
      w6[2] = fminf(fmaxf(b2f(q1.x) * scv + shv, 0.f), 6.f);
      w6[3] = fminf(fmaxf(b2f(q1.y) * scv + shv, 0.f), 6.f);
      w6[4] = fminf(fmaxf(b2f(q2.x) * scv + shv, 0.f), 6.f);
      w6[5] = fminf(fmaxf(b2f(q2.y) * scv + shv, 0.f), 6.f);
#pragma unroll
      for (int k = 0; k < 3; ++k) {     // in row ir feeds out row ir-k (tap k)
        int orow = ir - k;
        if (orow < 0 || orow >= 16) continue;
        float* A = accR[orow % 3];      // static under full unroll
#pragma unroll
        for (int j = 0; j < 4; ++j) {
          float t = w6[j] * wk[3 * k] + w6[j + 1] * wk[3 * k + 1] +
                    w6[j + 2] * wk[3 * k + 2];
          A[j] = (k == 0) ? t : A[j] + t;
        }
        if (k == 2) {
          ushort4v ov;
          ov.x = f2b(A[0]); ov.y = f2b(A[1]);
          ov.z = f2b(A[2]); ov.w = f2b(A[3]);
          *(ushort4v*)(op + orow * 16) = ov;
        }
      }
    }
  }
}

// ---------------- K5: bn2+relu6 then 1x1 conv 192->32 via MFMA --------------
// y3[32,256] = W3[32,192] @ bn2relu6(y2)[192,256]. W3 frags straight from wt
// (no LDS staging). Staging transpose via 4x4 register blocks.
__global__ __launch_bounds__(256) void k5_stage3(
    const bf16* __restrict__ y2, const unsigned short* __restrict__ wt,
    const float* __restrict__ sc2, const float* __restrict__ sh2,
    bf16* __restrict__ y3) {
  int g = remap_g(blockIdx.x);
  const unsigned short* w3g = wt + (size_t)g * HPAR + R2;   // [o2][k=192]
  __shared__ unsigned short bt[256 * PSTR];      // [sp=256][k-chunk=32], stride 36
  int tid = threadIdx.x;
  int w = tid >> 6, l = tid & 63;
  int lj = l & 15, kg = l >> 4;
  f32x4 acc[4][2] = {};
  const unsigned short* y2g = (const unsigned short*)y2 + (size_t)g * HID * SP2;
#pragma unroll 1
  for (int kc = 0; kc < 6; ++kc) {
    if (kc) __syncthreads();   // protect bt from previous chunk's readers
#pragma unroll
    for (int uu = 0; uu < 2; ++uu) {
      int u = tid + 256 * uu;
      int tq = u & 7, spq = u >> 3;           // k-quad, sp-quad
      int o0 = kc * 32 + tq * 4;
      float4 scv = *(const float4*)(sc2 + o0);
      float4 shv = *(const float4*)(sh2 + o0);
      unsigned short hbuf[4][4];
#pragma unroll
      for (int e = 0; e < 4; ++e) {
        ushort4v v = *(const ushort4v*)(y2g + (size_t)(o0 + e) * SP2 + spq * 4);
        float sce = ((const float*)&scv)[e], she = ((const float*)&shv)[e];
#pragma unroll
        for (int j = 0; j < 4; ++j) {
          float f = b2f(((const unsigned short*)&v)[j]) * sce + she;
          hbuf[e][j] = f2b(fminf(fmaxf(f, 0.f), 6.f));
        }
      }
#pragma unroll
      for (int j = 0; j < 4; ++j) {
        ushort4v wv;
        wv.x = hbuf[0][j]; wv.y = hbuf[1][j]; wv.z = hbuf[2][j]; wv.w = hbuf[3][j];
        *(ushort4v*)(bt + (spq * 4 + j) * PSTR + tq * 4) = wv;
      }
    }
    __syncthreads();
    Frag wf[2];
#pragma unroll
    for (int ot = 0; ot < 2; ++ot) {
      const unsigned short* wp = w3g + (ot * 16 + lj) * HID + kc * 32 + 4 * kg;
      wf[ot].h[0] = *(const short4v*)wp;
      wf[ot].h[1] = *(const short4v*)(wp + 16);
    }
#pragma unroll
    for (int sti = 0; sti < 4; ++sti) {
      const unsigned short* pb = bt + ((w + 4 * sti) * 16 + lj) * PSTR + 4 * kg;
      Frag tf;
      tf.h[0] = *(const short4v*)pb;
      tf.h[1] = *(const short4v*)(pb + 16);
#pragma unroll
      for (int ot = 0; ot < 2; ++ot)
        acc[sti][ot] = __builtin_amdgcn_mfma_f32_16x16x32_bf16(
            tf.v, wf[ot].v, acc[sti][ot], 0, 0, 0);
    }
  }
  // D[m=kg*4+r][n=lj]: m -> sp, n -> o2: direct short4 stores.
  unsigned short* yg3 = (unsigned short*)y3 + (size_t)g * 32 * SP2;
#pragma unroll
  for (int sti = 0; sti < 4; ++sti) {
    int spb = (w + 4 * sti) * 16 + kg * 4;
#pragma unroll
    for (int ot = 0; ot < 2; ++ot) {
      int o2 = ot * 16 + lj;
      short4v ov;
      ov.x = (short)f2b(acc[sti][ot][0]);
      ov.y = (short)f2b(acc[sti][ot][1]);
      ov.z = (short)f2b(acc[sti][ot][2]);
      ov.w = (short)f2b(acc[sti][ot][3]);
      *(short4v*)(yg3 + (size_t)o2 * SP2 + spb) = ov;
    }
  }
}

// ---------------- K7: bn3 + residual + scatter back (4 elems/thread) --------
__global__ __launch_bounds__(256) void k7_out(
    const float* __restrict__ x, const bf16* __restrict__ y3,
    const float* __restrict__ sc3, const float* __restrict__ sh3,
    float* __restrict__ out) {
  int idx = (blockIdx.x * 256 + threadIdx.x) * 4;  // 16*32*128*128 total
  int wcol = idx & 127;
  int hrow = (idx >> 7) & 127;
  int o2 = (idx >> 14) & 31;
  int bi = idx >> 19;
  int g = bi * 64 + (hrow >> 4) * 8 + (wcol >> 4);
  ushort4v u = *(const ushort4v*)((const unsigned short*)y3 +
                                  ((size_t)g * 32 + o2) * SP2 +
                                  ((hrow & 15) << 4) + (wcol & 15));
  float4 xv = *(const float4*)(x + idx);
  float sc = sc3[o2], sh = sh3[o2];
  float4 ov;
  ov.x = xv.x + b2f(u.x) * sc + sh;
  ov.y = xv.y + b2f(u.y) * sc + sh;
  ov.z = xv.z + b2f(u.z) * sc + sh;
  ov.w = xv.w + b2f(u.w) * sc + sh;
  *(float4*)(out + idx) = ov;
}

extern "C" void kernel_launch(void* const* d_in, const int* in_sizes, int n_in,
                              void* d_out, int out_size, void* d_ws, size_t ws_size,
                              hipStream_t stream) {
  const float* x  = (const float*)d_in[0];
  const float* s  = (const float*)d_in[1];
  const float* g1 = (const float*)d_in[2];
  const float* b1 = (const float*)d_in[3];
  const float* g2 = (const float*)d_in[4];
  const float* b2 = (const float*)d_in[5];
  const float* g3 = (const float*)d_in[6];
  const float* b3 = (const float*)d_in[7];
  float* out = (float*)d_out;

  char* ws = (char*)d_ws;
  float* stats = (float*)ws;
  float* sum1 = stats;        float* sq1 = stats + 192;
  float* sum2 = stats + 384;  float* sq2 = stats + 576;
  float* sum3 = stats + 768;  float* sq3 = stats + 800;
  float* sc1 = stats + 1024;  float* sh1 = stats + 1216;
  float* sc2 = stats + 1408;  float* sh2 = stats + 1600;
  float* sc3 = stats + 1792;  float* sh3 = stats + 1824;
  bf16* y1 = (bf16*)(ws + 8192);                       // 1024*192*324 bf16
  bf16* y2 = y1 + (size_t)NGRP * HID * SP1;            // 1024*192*256 bf16
  bf16* y3 = y1;                                       // alias: y1 dead by K5
  unsigned short* wt = (unsigned short*)(y2 + (size_t)NGRP * HID * SP2);  // [g][HPAR] bf16

  hipMemsetAsync(stats, 0, 832 * sizeof(float), stream);

  k0_wt<<<16 * 219, 256, 0, stream>>>(s, wt);
  k1_stage1<<<NGRP, 256, 0, stream>>>(x, wt, y1);
  k_stats<<<192 * 64, 256, 0, stream>>>(y1, HID, SP1, 16, sum1, sq1);
  k_bnp<<<1, 192, 0, stream>>>(sum1, sq1, g1, b1, sc1, sh1, HID, 1.f / (NGRP * (float)SP1));
  k3_dw<<<NGRP, 256, 0, stream>>>(y1, wt, sc1, sh1, y2);
  k_stats<<<192 * 64, 256, 0, stream>>>(y2, HID, SP2, 16, sum2, sq2);
  k_bnp<<<1, 192, 0, stream>>>(sum2, sq2, g2, b2, sc2, sh2, HID, 1.f / (NGRP * (float)SP2));
  k5_stage3<<<NGRP, 256, 0, stream>>>(y2, wt, sc2, sh2, y3);
  k_stats<<<32 * 64, 256, 0, stream>>>(y3, 32, SP2, 16, sum3, sq3);
  k_bnp<<<1, 32, 0, stream>>>(sum3, sq3, g3, b3, sc3, sh3, 32, 1.f / (NGRP * (float)SP2));
  k7_out<<<8192, 256, 0, stream>>>(x, y3, sc3, sh3, out);
}